// Round 1
// baseline (1393.192 us; speedup 1.0000x reference)
//
#include <hip/hip_runtime.h>

#define T_LEN 1024
#define C_DIM 2048
#define H_NUM 32
#define HS_DIM 64
#define FF_DIM 7168

typedef __attribute__((ext_vector_type(4))) float f32x4;
typedef __attribute__((ext_vector_type(8))) short short8;

__device__ __forceinline__ unsigned short f2bf(float f) {
  unsigned int u = __float_as_uint(f);
  unsigned int r = (u + 0x7FFFu + ((u >> 16) & 1u)) >> 16;
  return (unsigned short)r;
}

__device__ __forceinline__ void store_bf4(unsigned short* p, float4 v) {
  uint2 u;
  u.x = (unsigned int)f2bf(v.x) | ((unsigned int)f2bf(v.y) << 16);
  u.y = (unsigned int)f2bf(v.z) | ((unsigned int)f2bf(v.w) << 16);
  *(uint2*)p = u;
}

// ---------------- LayerNorm over C=2048, one block per token ----------------
__global__ __launch_bounds__(256) void ln_kernel(const float* __restrict__ x,
                                                 const float* __restrict__ w,
                                                 const float* __restrict__ b,
                                                 float* __restrict__ out) {
  const int t = blockIdx.x;
  const int tid = threadIdx.x;
  const float* xr = x + (size_t)t * C_DIM;
  float4 v1 = *(const float4*)(xr + tid * 8);
  float4 v2 = *(const float4*)(xr + tid * 8 + 4);
  float vals[8] = {v1.x, v1.y, v1.z, v1.w, v2.x, v2.y, v2.z, v2.w};
  float s = 0.f, sq = 0.f;
#pragma unroll
  for (int i = 0; i < 8; ++i) { s += vals[i]; sq = __builtin_fmaf(vals[i], vals[i], sq); }
#pragma unroll
  for (int o = 1; o < 64; o <<= 1) { s += __shfl_xor(s, o); sq += __shfl_xor(sq, o); }
  __shared__ float red[8];
  const int wave = tid >> 6, lane = tid & 63;
  if (lane == 0) { red[wave] = s; red[4 + wave] = sq; }
  __syncthreads();
  s = red[0] + red[1] + red[2] + red[3];
  sq = red[4] + red[5] + red[6] + red[7];
  const float mean = s * (1.f / C_DIM);
  const float var = sq * (1.f / C_DIM) - mean * mean;
  const float inv = rsqrtf(var + 1e-5f);
  float* orow = out + (size_t)t * C_DIM;
#pragma unroll
  for (int i = 0; i < 8; ++i) {
    int c = tid * 8 + i;
    orow[c] = (vals[i] - mean) * inv * w[c] + b[c];
  }
}

// ---------------- TimeMix token-shift mixes (4 outputs) ----------------
__global__ __launch_bounds__(256) void mix_att(const float* __restrict__ x1,
                                               const float* __restrict__ shift,
                                               const float* __restrict__ mr,
                                               const float* __restrict__ mk,
                                               const float* __restrict__ mv,
                                               const float* __restrict__ mg,
                                               float* __restrict__ xr, float* __restrict__ xk,
                                               float* __restrict__ xv, float* __restrict__ xg) {
  const int t = blockIdx.x;
  const int tid = threadIdx.x;
#pragma unroll
  for (int i = 0; i < 8; ++i) {
    int c = tid * 8 + i;
    size_t idx = (size_t)t * C_DIM + c;
    float cur = x1[idx];
    float prev = (t == 0) ? shift[c] : x1[idx - C_DIM];
    float a = mr[c]; xr[idx] = cur * a + prev * (1.f - a);
    a = mk[c]; xk[idx] = cur * a + prev * (1.f - a);
    a = mv[c]; xv[idx] = cur * a + prev * (1.f - a);
    a = mg[c]; xg[idx] = cur * a + prev * (1.f - a);
  }
}

// ---------------- ChannelMix token-shift mixes (2 outputs) ----------------
__global__ __launch_bounds__(256) void mix_cm(const float* __restrict__ x2,
                                              const float* __restrict__ shift,
                                              const float* __restrict__ mk,
                                              const float* __restrict__ mr,
                                              float* __restrict__ xk2, float* __restrict__ xr2) {
  const int t = blockIdx.x;
  const int tid = threadIdx.x;
#pragma unroll
  for (int i = 0; i < 8; ++i) {
    int c = tid * 8 + i;
    size_t idx = (size_t)t * C_DIM + c;
    float cur = x2[idx];
    float prev = (t == 0) ? shift[c] : x2[idx - C_DIM];
    float a = mk[c]; xk2[idx] = cur * a + prev * (1.f - a);
    a = mr[c]; xr2[idx] = cur * a + prev * (1.f - a);
  }
}

// ---------------- WKV v5 decay scan: one block per head ----------------
// threads: tid = v*4 + kg  (v = output column 0..63, kg = k-group 0..3, 16 k each)
__global__ __launch_bounds__(256) void wkv_scan(const float* __restrict__ kin,
                                                const float* __restrict__ vin,
                                                const float* __restrict__ rin,
                                                const float* __restrict__ decay,
                                                const float* __restrict__ faaaa,
                                                const float* __restrict__ s0,
                                                float* __restrict__ out) {
  const int h = blockIdx.x;
  const int tid = threadIdx.x;
  const int vcol = tid >> 2, kg = tid & 3;
  float s[16], w16[16], u16[16];
#pragma unroll
  for (int j = 0; j < 16; ++j) {
    int kidx = kg * 16 + j;
    w16[j] = expf(-expf(decay[h * HS_DIM + kidx]));
    u16[j] = faaaa[h * HS_DIM + kidx];
    s[j] = s0[((size_t)h * HS_DIM + kidx) * HS_DIM + vcol];
  }
  __shared__ float sbuf[2][3][HS_DIM];  // [slot][k/r/v][elem]
  if (tid < 192) {
    int which = tid >> 6, e = tid & 63;
    const float* src = which == 0 ? kin : (which == 1 ? rin : vin);
    sbuf[0][which][e] = src[(size_t)h * HS_DIM + e];
  }
  for (int t = 0; t < T_LEN; ++t) {
    __syncthreads();
    if (t + 1 < T_LEN && tid < 192) {
      int which = tid >> 6, e = tid & 63;
      const float* src = which == 0 ? kin : (which == 1 ? rin : vin);
      sbuf[(t + 1) & 1][which][e] = src[(size_t)(t + 1) * C_DIM + h * HS_DIM + e];
    }
    const int sl = t & 1;
    float kreg[16], rreg[16];
    const float4* kp = (const float4*)&sbuf[sl][0][kg * 16];
    const float4* rp = (const float4*)&sbuf[sl][1][kg * 16];
#pragma unroll
    for (int q = 0; q < 4; ++q) {
      float4 kv4 = kp[q], rv4 = rp[q];
      kreg[q * 4 + 0] = kv4.x; kreg[q * 4 + 1] = kv4.y; kreg[q * 4 + 2] = kv4.z; kreg[q * 4 + 3] = kv4.w;
      rreg[q * 4 + 0] = rv4.x; rreg[q * 4 + 1] = rv4.y; rreg[q * 4 + 2] = rv4.z; rreg[q * 4 + 3] = rv4.w;
    }
    const float vt = sbuf[sl][2][vcol];
    float acc = 0.f, ruk = 0.f;
#pragma unroll
    for (int j = 0; j < 16; ++j) {
      float kj = kreg[j], rj = rreg[j];
      acc = __builtin_fmaf(rj, s[j], acc);           // r . s  (old state)
      ruk = __builtin_fmaf(rj * u16[j], kj, ruk);    // r . (u*k)
      s[j] = __builtin_fmaf(s[j], w16[j], kj * vt);  // s = s*w + k*v
    }
    float part = __builtin_fmaf(ruk, vt, acc);
    part += __shfl_xor(part, 1);
    part += __shfl_xor(part, 2);
    if (kg == 0) out[(size_t)t * C_DIM + h * HS_DIM + vcol] = part;
  }
}

// ---------------- GroupNorm(out/8) * gn_w + gn_b, times silu(g) ----------------
__global__ __launch_bounds__(256) void gn_silu(const float* __restrict__ wkv,
                                               const float* __restrict__ gpre,
                                               const float* __restrict__ gw,
                                               const float* __restrict__ gb,
                                               float* __restrict__ zg) {
  const int idx = blockIdx.x * 4 + (threadIdx.x >> 6);  // group index = t*32 + h
  const int lane = threadIdx.x & 63;
  const int t = idx >> 5, h = idx & 31;
  const int c = h * HS_DIM + lane;
  const size_t off = (size_t)t * C_DIM + c;
  float z = wkv[off] * 0.125f;
  float s = z, sq = z * z;
#pragma unroll
  for (int o = 1; o < 64; o <<= 1) { s += __shfl_xor(s, o); sq += __shfl_xor(sq, o); }
  const float mean = s * (1.f / HS_DIM);
  const float var = sq * (1.f / HS_DIM) - mean * mean;
  const float val = (z - mean) * rsqrtf(var + 1e-5f) * gw[c] + gb[c];
  const float g = gpre[off];
  const float sig = 1.f / (1.f + __expf(-g));
  zg[off] = val * (g * sig);
}

// ---------------- GEMM: C[M,N] = A[M,K] * B[N,K]^T, f32 in, bf16 MFMA ----------------
struct GemmBatch {
  const float* A[4];
  const float* B[4];
  float* C[4];
  const float* E0[4];
  const float* E1[4];
};

// EPI: 0 = none, 1 = C = acc + E0, 2 = C = relu(acc)^2, 3 = C = E1 + sigmoid(E0)*acc
template <int EPI>
__global__ __launch_bounds__(256) void gemm_bt(GemmBatch gb, int M, int N, int K) {
  const int zb = blockIdx.z;
  const float* __restrict__ A = gb.A[zb];
  const float* __restrict__ B = gb.B[zb];
  float* __restrict__ C = gb.C[zb];
  const float* __restrict__ E0 = gb.E0[zb];
  const float* __restrict__ E1 = gb.E1[zb];

  __shared__ unsigned short As[128 * 40];  // 128 rows x 32 k, stride 40 (pad)
  __shared__ unsigned short Bs[128 * 40];

  const int tid = threadIdx.x;
  const int lane = tid & 63;
  const int wave = tid >> 6;
  const int wm = wave >> 1, wn = wave & 1;
  const int m0 = blockIdx.y * 128, n0 = blockIdx.x * 128;
  const int lrow = lane & 15;
  const int koff = (lane >> 4) * 8;

  f32x4 acc[4][4];
#pragma unroll
  for (int m = 0; m < 4; ++m)
#pragma unroll
    for (int n = 0; n < 4; ++n) acc[m][n] = (f32x4){0.f, 0.f, 0.f, 0.f};

  for (int kk = 0; kk < K; kk += 32) {
#pragma unroll
    for (int l = 0; l < 4; ++l) {
      int q = l * 256 + tid;        // float4 index within 128x32 tile
      int row = q >> 3, k4 = q & 7;
      float4 av = *(const float4*)(A + (size_t)(m0 + row) * K + kk + k4 * 4);
      float4 bv = *(const float4*)(B + (size_t)(n0 + row) * K + kk + k4 * 4);
      store_bf4(&As[row * 40 + k4 * 4], av);
      store_bf4(&Bs[row * 40 + k4 * 4], bv);
    }
    __syncthreads();
    short8 af[4], bf[4];
#pragma unroll
    for (int m = 0; m < 4; ++m)
      af[m] = *(const short8*)&As[(wm * 64 + m * 16 + lrow) * 40 + koff];
#pragma unroll
    for (int n = 0; n < 4; ++n)
      bf[n] = *(const short8*)&Bs[(wn * 64 + n * 16 + lrow) * 40 + koff];
#pragma unroll
    for (int m = 0; m < 4; ++m)
#pragma unroll
      for (int n = 0; n < 4; ++n)
        acc[m][n] = __builtin_amdgcn_mfma_f32_16x16x32_bf16(af[m], bf[n], acc[m][n], 0, 0, 0);
    __syncthreads();
  }

#pragma unroll
  for (int m = 0; m < 4; ++m) {
#pragma unroll
    for (int n = 0; n < 4; ++n) {
#pragma unroll
      for (int j = 0; j < 4; ++j) {
        int row = m0 + wm * 64 + m * 16 + ((lane >> 4) << 2) + j;
        int col = n0 + wn * 64 + n * 16 + lrow;
        size_t idx = (size_t)row * N + col;
        float v = acc[m][n][j];
        if (EPI == 1) {
          v += E0[idx];
        } else if (EPI == 2) {
          float tpos = v > 0.f ? v : 0.f;
          v = tpos * tpos;
        } else if (EPI == 3) {
          float sg = 1.f / (1.f + __expf(-E0[idx]));
          v = E1[idx] + sg * v;
        }
        C[idx] = v;
      }
    }
  }
}

extern "C" void kernel_launch(void* const* d_in, const int* in_sizes, int n_in,
                              void* d_out, int out_size, void* d_ws, size_t ws_size,
                              hipStream_t stream) {
  (void)in_sizes; (void)n_in; (void)out_size; (void)ws_size;
  const float* x         = (const float*)d_in[0];
  const float* att_shift = (const float*)d_in[1];
  const float* wkv_state = (const float*)d_in[2];
  const float* ffn_shift = (const float*)d_in[3];
  const float* ln1_w = (const float*)d_in[4];
  const float* ln1_b = (const float*)d_in[5];
  const float* ln2_w = (const float*)d_in[6];
  const float* ln2_b = (const float*)d_in[7];
  const float* tm_k = (const float*)d_in[8];
  const float* tm_v = (const float*)d_in[9];
  const float* tm_r = (const float*)d_in[10];
  const float* tm_g = (const float*)d_in[11];
  const float* time_decay = (const float*)d_in[12];
  const float* time_faaaa = (const float*)d_in[13];
  const float* Wr = (const float*)d_in[14];
  const float* Wk = (const float*)d_in[15];
  const float* Wv = (const float*)d_in[16];
  const float* Wo = (const float*)d_in[17];
  const float* Wg = (const float*)d_in[18];
  const float* gn_w = (const float*)d_in[19];
  const float* gn_b = (const float*)d_in[20];
  const float* cm_k = (const float*)d_in[21];
  const float* cm_r = (const float*)d_in[22];
  const float* Wck = (const float*)d_in[23];
  const float* Wcr = (const float*)d_in[24];
  const float* Wcv = (const float*)d_in[25];
  float* out = (float*)d_out;

  float* wsf = (float*)d_ws;
  const size_t R = (size_t)T_LEN * C_DIM;  // 2097152 floats per region
  float* x1   = wsf + 0 * R;   // later aliased: wkv_out
  float* xr   = wsf + 1 * R;   // later: x2
  float* xk   = wsf + 2 * R;   // later: xk2
  float* xv   = wsf + 3 * R;   // later: xr2
  float* xg   = wsf + 4 * R;   // later: s1
  float* rb   = wsf + 5 * R;   // r; later kk spans rb .. rb+3.5R
  float* kb   = wsf + 6 * R;
  float* vb   = wsf + 7 * R;
  float* gpre = wsf + 8 * R;
  float* zg   = wsf + 9 * R;
  float* xnew = wsf + 10 * R;
  float* wkvo = x1;
  float* x2   = xr;
  float* xk2  = xk;
  float* xr2  = xv;
  float* s1   = xg;
  float* kkb  = rb;

  dim3 blk(256);

  // --- TimeMix ---
  ln_kernel<<<T_LEN, blk, 0, stream>>>(x, ln1_w, ln1_b, x1);
  mix_att<<<T_LEN, blk, 0, stream>>>(x1, att_shift, tm_r, tm_k, tm_v, tm_g, xr, xk, xv, xg);
  GemmBatch g4 = {};
  g4.A[0] = xr; g4.B[0] = Wr; g4.C[0] = rb;
  g4.A[1] = xk; g4.B[1] = Wk; g4.C[1] = kb;
  g4.A[2] = xv; g4.B[2] = Wv; g4.C[2] = vb;
  g4.A[3] = xg; g4.B[3] = Wg; g4.C[3] = gpre;
  gemm_bt<0><<<dim3(16, 8, 4), blk, 0, stream>>>(g4, T_LEN, C_DIM, C_DIM);
  wkv_scan<<<H_NUM, blk, 0, stream>>>(kb, vb, rb, time_decay, time_faaaa, wkv_state, wkvo);
  gn_silu<<<(T_LEN * H_NUM) / 4, blk, 0, stream>>>(wkvo, gpre, gn_w, gn_b, zg);
  GemmBatch go = {};
  go.A[0] = zg; go.B[0] = Wo; go.C[0] = xnew; go.E0[0] = x;
  gemm_bt<1><<<dim3(16, 8, 1), blk, 0, stream>>>(go, T_LEN, C_DIM, C_DIM);

  // --- ChannelMix ---
  ln_kernel<<<T_LEN, blk, 0, stream>>>(xnew, ln2_w, ln2_b, x2);
  mix_cm<<<T_LEN, blk, 0, stream>>>(x2, ffn_shift, cm_k, cm_r, xk2, xr2);
  GemmBatch gk = {};
  gk.A[0] = xk2; gk.B[0] = Wck; gk.C[0] = kkb;
  gemm_bt<2><<<dim3(56, 8, 1), blk, 0, stream>>>(gk, T_LEN, FF_DIM, C_DIM);
  GemmBatch gr = {};
  gr.A[0] = xr2; gr.B[0] = Wcr; gr.C[0] = s1;
  gemm_bt<0><<<dim3(16, 8, 1), blk, 0, stream>>>(gr, T_LEN, C_DIM, C_DIM);
  GemmBatch gv = {};
  gv.A[0] = kkb; gv.B[0] = Wcv; gv.C[0] = out; gv.E0[0] = s1; gv.E1[0] = xnew;
  gemm_bt<3><<<dim3(16, 8, 1), blk, 0, stream>>>(gv, T_LEN, C_DIM, FF_DIM);
}

// Round 2
// 842.368 us; speedup vs baseline: 1.6539x; 1.6539x over previous
//
#include <hip/hip_runtime.h>

#define T_LEN 1024
#define C_DIM 2048
#define H_NUM 32
#define HS_DIM 64
#define FF_DIM 7168
#define CHUNK 64
#define NCHUNK (T_LEN / CHUNK)

typedef __attribute__((ext_vector_type(4))) float f32x4;
typedef __attribute__((ext_vector_type(8))) short short8;

__device__ __forceinline__ unsigned short f2bf(float f) {
  unsigned int u = __float_as_uint(f);
  unsigned int r = (u + 0x7FFFu + ((u >> 16) & 1u)) >> 16;
  return (unsigned short)r;
}

__device__ __forceinline__ void store_bf4(unsigned short* p, float4 v) {
  uint2 u;
  u.x = (unsigned int)f2bf(v.x) | ((unsigned int)f2bf(v.y) << 16);
  u.y = (unsigned int)f2bf(v.z) | ((unsigned int)f2bf(v.w) << 16);
  *(uint2*)p = u;
}

// ---------------- LayerNorm over C=2048, one block per token ----------------
__global__ __launch_bounds__(256) void ln_kernel(const float* __restrict__ x,
                                                 const float* __restrict__ w,
                                                 const float* __restrict__ b,
                                                 float* __restrict__ out) {
  const int t = blockIdx.x;
  const int tid = threadIdx.x;
  const float* xr = x + (size_t)t * C_DIM;
  float4 v1 = *(const float4*)(xr + tid * 8);
  float4 v2 = *(const float4*)(xr + tid * 8 + 4);
  float vals[8] = {v1.x, v1.y, v1.z, v1.w, v2.x, v2.y, v2.z, v2.w};
  float s = 0.f, sq = 0.f;
#pragma unroll
  for (int i = 0; i < 8; ++i) { s += vals[i]; sq = __builtin_fmaf(vals[i], vals[i], sq); }
#pragma unroll
  for (int o = 1; o < 64; o <<= 1) { s += __shfl_xor(s, o); sq += __shfl_xor(sq, o); }
  __shared__ float red[8];
  const int wave = tid >> 6, lane = tid & 63;
  if (lane == 0) { red[wave] = s; red[4 + wave] = sq; }
  __syncthreads();
  s = red[0] + red[1] + red[2] + red[3];
  sq = red[4] + red[5] + red[6] + red[7];
  const float mean = s * (1.f / C_DIM);
  const float var = sq * (1.f / C_DIM) - mean * mean;
  const float inv = rsqrtf(var + 1e-5f);
  float* orow = out + (size_t)t * C_DIM;
#pragma unroll
  for (int i = 0; i < 8; ++i) {
    int c = tid * 8 + i;
    orow[c] = (vals[i] - mean) * inv * w[c] + b[c];
  }
}

// ---------------- TimeMix token-shift mixes (4 outputs) ----------------
__global__ __launch_bounds__(256) void mix_att(const float* __restrict__ x1,
                                               const float* __restrict__ shift,
                                               const float* __restrict__ mr,
                                               const float* __restrict__ mk,
                                               const float* __restrict__ mv,
                                               const float* __restrict__ mg,
                                               float* __restrict__ xr, float* __restrict__ xk,
                                               float* __restrict__ xv, float* __restrict__ xg) {
  const int t = blockIdx.x;
  const int tid = threadIdx.x;
#pragma unroll
  for (int i = 0; i < 8; ++i) {
    int c = tid * 8 + i;
    size_t idx = (size_t)t * C_DIM + c;
    float cur = x1[idx];
    float prev = (t == 0) ? shift[c] : x1[idx - C_DIM];
    float a = mr[c]; xr[idx] = cur * a + prev * (1.f - a);
    a = mk[c]; xk[idx] = cur * a + prev * (1.f - a);
    a = mv[c]; xv[idx] = cur * a + prev * (1.f - a);
    a = mg[c]; xg[idx] = cur * a + prev * (1.f - a);
  }
}

// ---------------- ChannelMix token-shift mixes (2 outputs) ----------------
__global__ __launch_bounds__(256) void mix_cm(const float* __restrict__ x2,
                                              const float* __restrict__ shift,
                                              const float* __restrict__ mk,
                                              const float* __restrict__ mr,
                                              float* __restrict__ xk2, float* __restrict__ xr2) {
  const int t = blockIdx.x;
  const int tid = threadIdx.x;
#pragma unroll
  for (int i = 0; i < 8; ++i) {
    int c = tid * 8 + i;
    size_t idx = (size_t)t * C_DIM + c;
    float cur = x2[idx];
    float prev = (t == 0) ? shift[c] : x2[idx - C_DIM];
    float a = mk[c]; xk2[idx] = cur * a + prev * (1.f - a);
    a = mr[c]; xr2[idx] = cur * a + prev * (1.f - a);
  }
}

// ======================= Chunk-parallel WKV v5 scan =======================
// Thread mapping in all three passes: tid = vcol*4 + kg; thread owns state
// s[kg*16+j][vcol] for j in 0..15.

// Pass A: per-chunk summary A_c = sum_j w^(L-1-j) k_j v_j^T.
// grid (NCHUNK, H_NUM)
__global__ __launch_bounds__(256) void wkv_chunk_sum(const float* __restrict__ kin,
                                                     const float* __restrict__ vin,
                                                     const float* __restrict__ decay,
                                                     float* __restrict__ Abuf) {
  const int c = blockIdx.x, h = blockIdx.y;
  const int tid = threadIdx.x;
  const int vcol = tid >> 2, kg = tid & 3;
  __shared__ float ks[CHUNK][HS_DIM];
  __shared__ float vs[CHUNK][HS_DIM];
  for (int i = tid; i < CHUNK * HS_DIM / 4; i += 256) {
    int row = i >> 4, q = i & 15;
    size_t g = (size_t)(c * CHUNK + row) * C_DIM + h * HS_DIM + q * 4;
    *(float4*)&ks[row][q * 4] = *(const float4*)(kin + g);
    *(float4*)&vs[row][q * 4] = *(const float4*)(vin + g);
  }
  float w16[16], s[16];
#pragma unroll
  for (int j = 0; j < 16; ++j) {
    w16[j] = expf(-expf(decay[h * HS_DIM + kg * 16 + j]));
    s[j] = 0.f;
  }
  __syncthreads();
  for (int t = 0; t < CHUNK; ++t) {
    const float vt = vs[t][vcol];
    const float4* kp = (const float4*)&ks[t][kg * 16];
#pragma unroll
    for (int q = 0; q < 4; ++q) {
      float4 k4 = kp[q];
      s[q * 4 + 0] = __builtin_fmaf(s[q * 4 + 0], w16[q * 4 + 0], k4.x * vt);
      s[q * 4 + 1] = __builtin_fmaf(s[q * 4 + 1], w16[q * 4 + 1], k4.y * vt);
      s[q * 4 + 2] = __builtin_fmaf(s[q * 4 + 2], w16[q * 4 + 2], k4.z * vt);
      s[q * 4 + 3] = __builtin_fmaf(s[q * 4 + 3], w16[q * 4 + 3], k4.w * vt);
    }
  }
  const size_t base = (((size_t)h * NCHUNK + c) * HS_DIM + kg * 16) * HS_DIM + vcol;
#pragma unroll
  for (int j = 0; j < 16; ++j) Abuf[base + (size_t)j * HS_DIM] = s[j];
}

// Pass B: chunk-start states. s_{c+1} = s_c * w^L + A_c. grid (H_NUM)
__global__ __launch_bounds__(256) void wkv_chain(const float* __restrict__ Abuf,
                                                 const float* __restrict__ s0,
                                                 const float* __restrict__ decay,
                                                 float* __restrict__ Sbuf) {
  const int h = blockIdx.x;
  const int tid = threadIdx.x;
  const int vcol = tid >> 2, kg = tid & 3;
  float wL[16], s[16];
#pragma unroll
  for (int j = 0; j < 16; ++j) {
    int kidx = kg * 16 + j;
    wL[j] = expf(-(float)CHUNK * expf(decay[h * HS_DIM + kidx]));
    s[j] = s0[((size_t)h * HS_DIM + kidx) * HS_DIM + vcol];
  }
  for (int c = 0; c < NCHUNK; ++c) {
    const size_t base = (((size_t)h * NCHUNK + c) * HS_DIM + kg * 16) * HS_DIM + vcol;
#pragma unroll
    for (int j = 0; j < 16; ++j) {
      Sbuf[base + (size_t)j * HS_DIM] = s[j];
      s[j] = __builtin_fmaf(s[j], wL[j], Abuf[base + (size_t)j * HS_DIM]);
    }
  }
}

// Pass C: replay the exact reference scan within each chunk from its
// chunk-start state. grid (NCHUNK, H_NUM)
__global__ __launch_bounds__(256) void wkv_chunk_out(const float* __restrict__ kin,
                                                     const float* __restrict__ vin,
                                                     const float* __restrict__ rin,
                                                     const float* __restrict__ decay,
                                                     const float* __restrict__ faaaa,
                                                     const float* __restrict__ Sbuf,
                                                     float* __restrict__ outp) {
  const int c = blockIdx.x, h = blockIdx.y;
  const int tid = threadIdx.x;
  const int vcol = tid >> 2, kg = tid & 3;
  __shared__ float ks[CHUNK][HS_DIM];
  __shared__ float rs[CHUNK][HS_DIM];
  __shared__ float vs[CHUNK][HS_DIM];
  for (int i = tid; i < CHUNK * HS_DIM / 4; i += 256) {
    int row = i >> 4, q = i & 15;
    size_t g = (size_t)(c * CHUNK + row) * C_DIM + h * HS_DIM + q * 4;
    *(float4*)&ks[row][q * 4] = *(const float4*)(kin + g);
    *(float4*)&rs[row][q * 4] = *(const float4*)(rin + g);
    *(float4*)&vs[row][q * 4] = *(const float4*)(vin + g);
  }
  float w16[16], u16[16], s[16];
  const size_t sbase = (((size_t)h * NCHUNK + c) * HS_DIM + kg * 16) * HS_DIM + vcol;
#pragma unroll
  for (int j = 0; j < 16; ++j) {
    int kidx = kg * 16 + j;
    w16[j] = expf(-expf(decay[h * HS_DIM + kidx]));
    u16[j] = faaaa[h * HS_DIM + kidx];
    s[j] = Sbuf[sbase + (size_t)j * HS_DIM];
  }
  __syncthreads();
  for (int t = 0; t < CHUNK; ++t) {
    const float vt = vs[t][vcol];
    const float4* kp = (const float4*)&ks[t][kg * 16];
    const float4* rp = (const float4*)&rs[t][kg * 16];
    float acc = 0.f, ruk = 0.f;
#pragma unroll
    for (int q = 0; q < 4; ++q) {
      float4 k4 = kp[q], r4 = rp[q];
      acc = __builtin_fmaf(r4.x, s[q * 4 + 0], acc);
      ruk = __builtin_fmaf(r4.x * u16[q * 4 + 0], k4.x, ruk);
      s[q * 4 + 0] = __builtin_fmaf(s[q * 4 + 0], w16[q * 4 + 0], k4.x * vt);
      acc = __builtin_fmaf(r4.y, s[q * 4 + 1], acc);
      ruk = __builtin_fmaf(r4.y * u16[q * 4 + 1], k4.y, ruk);
      s[q * 4 + 1] = __builtin_fmaf(s[q * 4 + 1], w16[q * 4 + 1], k4.y * vt);
      acc = __builtin_fmaf(r4.z, s[q * 4 + 2], acc);
      ruk = __builtin_fmaf(r4.z * u16[q * 4 + 2], k4.z, ruk);
      s[q * 4 + 2] = __builtin_fmaf(s[q * 4 + 2], w16[q * 4 + 2], k4.z * vt);
      acc = __builtin_fmaf(r4.w, s[q * 4 + 3], acc);
      ruk = __builtin_fmaf(r4.w * u16[q * 4 + 3], k4.w, ruk);
      s[q * 4 + 3] = __builtin_fmaf(s[q * 4 + 3], w16[q * 4 + 3], k4.w * vt);
    }
    float part = __builtin_fmaf(ruk, vt, acc);
    part += __shfl_xor(part, 1);
    part += __shfl_xor(part, 2);
    if (kg == 0) outp[(size_t)(c * CHUNK + t) * C_DIM + h * HS_DIM + vcol] = part;
  }
}

// ---------------- GroupNorm(out/8) * gn_w + gn_b, times silu(g) ----------------
__global__ __launch_bounds__(256) void gn_silu(const float* __restrict__ wkv,
                                               const float* __restrict__ gpre,
                                               const float* __restrict__ gw,
                                               const float* __restrict__ gb,
                                               float* __restrict__ zg) {
  const int idx = blockIdx.x * 4 + (threadIdx.x >> 6);  // group index = t*32 + h
  const int lane = threadIdx.x & 63;
  const int t = idx >> 5, h = idx & 31;
  const int c = h * HS_DIM + lane;
  const size_t off = (size_t)t * C_DIM + c;
  float z = wkv[off] * 0.125f;
  float s = z, sq = z * z;
#pragma unroll
  for (int o = 1; o < 64; o <<= 1) { s += __shfl_xor(s, o); sq += __shfl_xor(sq, o); }
  const float mean = s * (1.f / HS_DIM);
  const float var = sq * (1.f / HS_DIM) - mean * mean;
  const float val = (z - mean) * rsqrtf(var + 1e-5f) * gw[c] + gb[c];
  const float g = gpre[off];
  const float sig = 1.f / (1.f + __expf(-g));
  zg[off] = val * (g * sig);
}

// ---------------- GEMM: C[M,N] = A[M,K] * B[N,K]^T, f32 in, bf16 MFMA ----------------
struct GemmBatch {
  const float* A[4];
  const float* B[4];
  float* C[4];
  const float* E0[4];
  const float* E1[4];
};

// EPI: 0 = none, 1 = C = acc + E0, 2 = C = relu(acc)^2, 3 = C = E1 + sigmoid(E0)*acc
template <int EPI>
__global__ __launch_bounds__(256) void gemm_bt(GemmBatch gb, int M, int N, int K) {
  const int zb = blockIdx.z;
  const float* __restrict__ A = gb.A[zb];
  const float* __restrict__ B = gb.B[zb];
  float* __restrict__ C = gb.C[zb];
  const float* __restrict__ E0 = gb.E0[zb];
  const float* __restrict__ E1 = gb.E1[zb];

  __shared__ unsigned short As[128 * 40];  // 128 rows x 32 k, stride 40 (pad)
  __shared__ unsigned short Bs[128 * 40];

  const int tid = threadIdx.x;
  const int lane = tid & 63;
  const int wave = tid >> 6;
  const int wm = wave >> 1, wn = wave & 1;
  const int m0 = blockIdx.y * 128, n0 = blockIdx.x * 128;
  const int lrow = lane & 15;
  const int koff = (lane >> 4) * 8;

  f32x4 acc[4][4];
#pragma unroll
  for (int m = 0; m < 4; ++m)
#pragma unroll
    for (int n = 0; n < 4; ++n) acc[m][n] = (f32x4){0.f, 0.f, 0.f, 0.f};

  for (int kk = 0; kk < K; kk += 32) {
#pragma unroll
    for (int l = 0; l < 4; ++l) {
      int q = l * 256 + tid;        // float4 index within 128x32 tile
      int row = q >> 3, k4 = q & 7;
      float4 av = *(const float4*)(A + (size_t)(m0 + row) * K + kk + k4 * 4);
      float4 bv = *(const float4*)(B + (size_t)(n0 + row) * K + kk + k4 * 4);
      store_bf4(&As[row * 40 + k4 * 4], av);
      store_bf4(&Bs[row * 40 + k4 * 4], bv);
    }
    __syncthreads();
    short8 af[4], bf[4];
#pragma unroll
    for (int m = 0; m < 4; ++m)
      af[m] = *(const short8*)&As[(wm * 64 + m * 16 + lrow) * 40 + koff];
#pragma unroll
    for (int n = 0; n < 4; ++n)
      bf[n] = *(const short8*)&Bs[(wn * 64 + n * 16 + lrow) * 40 + koff];
#pragma unroll
    for (int m = 0; m < 4; ++m)
#pragma unroll
      for (int n = 0; n < 4; ++n)
        acc[m][n] = __builtin_amdgcn_mfma_f32_16x16x32_bf16(af[m], bf[n], acc[m][n], 0, 0, 0);
    __syncthreads();
  }

#pragma unroll
  for (int m = 0; m < 4; ++m) {
#pragma unroll
    for (int n = 0; n < 4; ++n) {
#pragma unroll
      for (int j = 0; j < 4; ++j) {
        int row = m0 + wm * 64 + m * 16 + ((lane >> 4) << 2) + j;
        int col = n0 + wn * 64 + n * 16 + lrow;
        size_t idx = (size_t)row * N + col;
        float v = acc[m][n][j];
        if (EPI == 1) {
          v += E0[idx];
        } else if (EPI == 2) {
          float tpos = v > 0.f ? v : 0.f;
          v = tpos * tpos;
        } else if (EPI == 3) {
          float sg = 1.f / (1.f + __expf(-E0[idx]));
          v = E1[idx] + sg * v;
        }
        C[idx] = v;
      }
    }
  }
}

extern "C" void kernel_launch(void* const* d_in, const int* in_sizes, int n_in,
                              void* d_out, int out_size, void* d_ws, size_t ws_size,
                              hipStream_t stream) {
  (void)in_sizes; (void)n_in; (void)out_size; (void)ws_size;
  const float* x         = (const float*)d_in[0];
  const float* att_shift = (const float*)d_in[1];
  const float* wkv_state = (const float*)d_in[2];
  const float* ffn_shift = (const float*)d_in[3];
  const float* ln1_w = (const float*)d_in[4];
  const float* ln1_b = (const float*)d_in[5];
  const float* ln2_w = (const float*)d_in[6];
  const float* ln2_b = (const float*)d_in[7];
  const float* tm_k = (const float*)d_in[8];
  const float* tm_v = (const float*)d_in[9];
  const float* tm_r = (const float*)d_in[10];
  const float* tm_g = (const float*)d_in[11];
  const float* time_decay = (const float*)d_in[12];
  const float* time_faaaa = (const float*)d_in[13];
  const float* Wr = (const float*)d_in[14];
  const float* Wk = (const float*)d_in[15];
  const float* Wv = (const float*)d_in[16];
  const float* Wo = (const float*)d_in[17];
  const float* Wg = (const float*)d_in[18];
  const float* gn_w = (const float*)d_in[19];
  const float* gn_b = (const float*)d_in[20];
  const float* cm_k = (const float*)d_in[21];
  const float* cm_r = (const float*)d_in[22];
  const float* Wck = (const float*)d_in[23];
  const float* Wcr = (const float*)d_in[24];
  const float* Wcv = (const float*)d_in[25];
  float* out = (float*)d_out;

  float* wsf = (float*)d_ws;
  const size_t R = (size_t)T_LEN * C_DIM;  // 2097152 floats per region
  float* x1   = wsf + 0 * R;   // later aliased: wkv_out
  float* xr   = wsf + 1 * R;   // later: x2
  float* xk   = wsf + 2 * R;   // later: Abuf, then xk2
  float* xv   = wsf + 3 * R;   // later: Sbuf, then xr2
  float* xg   = wsf + 4 * R;   // later: s1
  float* rb   = wsf + 5 * R;   // r; later kk spans rb .. rb+3.5R
  float* kb   = wsf + 6 * R;
  float* vb   = wsf + 7 * R;
  float* gpre = wsf + 8 * R;
  float* zg   = wsf + 9 * R;
  float* xnew = wsf + 10 * R;
  float* wkvo = x1;
  float* Abuf = xk;   // 32*16*64*64 = R floats exactly
  float* Sbuf = xv;
  float* x2   = xr;
  float* xk2  = xk;
  float* xr2  = xv;
  float* s1   = xg;
  float* kkb  = rb;

  dim3 blk(256);

  // --- TimeMix ---
  ln_kernel<<<T_LEN, blk, 0, stream>>>(x, ln1_w, ln1_b, x1);
  mix_att<<<T_LEN, blk, 0, stream>>>(x1, att_shift, tm_r, tm_k, tm_v, tm_g, xr, xk, xv, xg);
  GemmBatch g4 = {};
  g4.A[0] = xr; g4.B[0] = Wr; g4.C[0] = rb;
  g4.A[1] = xk; g4.B[1] = Wk; g4.C[1] = kb;
  g4.A[2] = xv; g4.B[2] = Wv; g4.C[2] = vb;
  g4.A[3] = xg; g4.B[3] = Wg; g4.C[3] = gpre;
  gemm_bt<0><<<dim3(16, 8, 4), blk, 0, stream>>>(g4, T_LEN, C_DIM, C_DIM);

  // chunk-parallel WKV scan
  wkv_chunk_sum<<<dim3(NCHUNK, H_NUM), blk, 0, stream>>>(kb, vb, time_decay, Abuf);
  wkv_chain<<<H_NUM, blk, 0, stream>>>(Abuf, wkv_state, time_decay, Sbuf);
  wkv_chunk_out<<<dim3(NCHUNK, H_NUM), blk, 0, stream>>>(kb, vb, rb, time_decay, time_faaaa,
                                                         Sbuf, wkvo);

  gn_silu<<<(T_LEN * H_NUM) / 4, blk, 0, stream>>>(wkvo, gpre, gn_w, gn_b, zg);
  GemmBatch go = {};
  go.A[0] = zg; go.B[0] = Wo; go.C[0] = xnew; go.E0[0] = x;
  gemm_bt<1><<<dim3(16, 8, 1), blk, 0, stream>>>(go, T_LEN, C_DIM, C_DIM);

  // --- ChannelMix ---
  ln_kernel<<<T_LEN, blk, 0, stream>>>(xnew, ln2_w, ln2_b, x2);
  mix_cm<<<T_LEN, blk, 0, stream>>>(x2, ffn_shift, cm_k, cm_r, xk2, xr2);
  GemmBatch gk = {};
  gk.A[0] = xk2; gk.B[0] = Wck; gk.C[0] = kkb;
  gemm_bt<2><<<dim3(56, 8, 1), blk, 0, stream>>>(gk, T_LEN, FF_DIM, C_DIM);
  GemmBatch gr = {};
  gr.A[0] = xr2; gr.B[0] = Wcr; gr.C[0] = s1;
  gemm_bt<0><<<dim3(16, 8, 1), blk, 0, stream>>>(gr, T_LEN, C_DIM, C_DIM);
  GemmBatch gv = {};
  gv.A[0] = kkb; gv.B[0] = Wcv; gv.C[0] = out; gv.E0[0] = s1; gv.E1[0] = xnew;
  gemm_bt<3><<<dim3(16, 8, 1), blk, 0, stream>>>(gv, T_LEN, C_DIM, FF_DIM);
}

// Round 3
// 497.182 us; speedup vs baseline: 2.8022x; 1.6943x over previous
//
#include <hip/hip_runtime.h>

#define T_LEN 1024
#define C_DIM 2048
#define H_NUM 32
#define HS_DIM 64
#define FF_DIM 7168
#define CHUNK 64
#define NCHUNK (T_LEN / CHUNK)

typedef __attribute__((ext_vector_type(4))) float f32x4;
typedef __attribute__((ext_vector_type(8))) short short8;

__device__ __forceinline__ unsigned short f2bf(float f) {
  unsigned int u = __float_as_uint(f);
  unsigned int r = (u + 0x7FFFu + ((u >> 16) & 1u)) >> 16;
  return (unsigned short)r;
}

__device__ __forceinline__ short8 pack_bf8(float4 a, float4 b) {
  short8 o;
  o[0] = (short)f2bf(a.x); o[1] = (short)f2bf(a.y);
  o[2] = (short)f2bf(a.z); o[3] = (short)f2bf(a.w);
  o[4] = (short)f2bf(b.x); o[5] = (short)f2bf(b.y);
  o[6] = (short)f2bf(b.z); o[7] = (short)f2bf(b.w);
  return o;
}

__device__ __forceinline__ void gl_lds16(const void* g, void* l) {
  __builtin_amdgcn_global_load_lds(
      (const __attribute__((address_space(1))) unsigned int*)g,
      (__attribute__((address_space(3))) unsigned int*)l, 16, 0, 0);
}

// ---------------- f32 -> bf16 convert (weights) ----------------
__global__ __launch_bounds__(256) void cvt_bf16(const float* __restrict__ s,
                                                unsigned short* __restrict__ d, int n8) {
  for (int i = blockIdx.x * 256 + threadIdx.x; i < n8; i += gridDim.x * 256) {
    const float4* p = (const float4*)(s + (size_t)i * 8);
    short8 o = pack_bf8(p[0], p[1]);
    *(short8*)(d + (size_t)i * 8) = o;
  }
}

// ---------------- LayerNorm over C=2048, one block per token ----------------
__global__ __launch_bounds__(256) void ln_kernel(const float* __restrict__ x,
                                                 const float* __restrict__ w,
                                                 const float* __restrict__ b,
                                                 float* __restrict__ out) {
  const int t = blockIdx.x;
  const int tid = threadIdx.x;
  const float* xr = x + (size_t)t * C_DIM;
  float4 v1 = *(const float4*)(xr + tid * 8);
  float4 v2 = *(const float4*)(xr + tid * 8 + 4);
  float vals[8] = {v1.x, v1.y, v1.z, v1.w, v2.x, v2.y, v2.z, v2.w};
  float s = 0.f, sq = 0.f;
#pragma unroll
  for (int i = 0; i < 8; ++i) { s += vals[i]; sq = __builtin_fmaf(vals[i], vals[i], sq); }
#pragma unroll
  for (int o = 1; o < 64; o <<= 1) { s += __shfl_xor(s, o); sq += __shfl_xor(sq, o); }
  __shared__ float red[8];
  const int wave = tid >> 6, lane = tid & 63;
  if (lane == 0) { red[wave] = s; red[4 + wave] = sq; }
  __syncthreads();
  s = red[0] + red[1] + red[2] + red[3];
  sq = red[4] + red[5] + red[6] + red[7];
  const float mean = s * (1.f / C_DIM);
  const float var = sq * (1.f / C_DIM) - mean * mean;
  const float inv = rsqrtf(var + 1e-5f);
  float* orow = out + (size_t)t * C_DIM;
#pragma unroll
  for (int i = 0; i < 8; ++i) {
    int c = tid * 8 + i;
    orow[c] = (vals[i] - mean) * inv * w[c] + b[c];
  }
}

// ---------------- TimeMix token-shift mixes -> bf16 ----------------
__global__ __launch_bounds__(256) void mix_att(const float* __restrict__ x1,
                                               const float* __restrict__ shift,
                                               const float* __restrict__ mr,
                                               const float* __restrict__ mk,
                                               const float* __restrict__ mv,
                                               const float* __restrict__ mg,
                                               unsigned short* __restrict__ xr,
                                               unsigned short* __restrict__ xk,
                                               unsigned short* __restrict__ xv,
                                               unsigned short* __restrict__ xg) {
  const int t = blockIdx.x;
  const int tid = threadIdx.x;
  const int c0 = tid * 8;
  const size_t idx = (size_t)t * C_DIM + c0;
  float cur[8], prev[8];
  *(float4*)&cur[0] = *(const float4*)(x1 + idx);
  *(float4*)&cur[4] = *(const float4*)(x1 + idx + 4);
  if (t == 0) {
    *(float4*)&prev[0] = *(const float4*)(shift + c0);
    *(float4*)&prev[4] = *(const float4*)(shift + c0 + 4);
  } else {
    *(float4*)&prev[0] = *(const float4*)(x1 + idx - C_DIM);
    *(float4*)&prev[4] = *(const float4*)(x1 + idx - C_DIM + 4);
  }
  float4 oa, ob;
  const float* mix[4] = {mr, mk, mv, mg};
  unsigned short* dst[4] = {xr, xk, xv, xg};
#pragma unroll
  for (int which = 0; which < 4; ++which) {
    const float* m = mix[which];
    float o[8];
#pragma unroll
    for (int i = 0; i < 8; ++i) {
      float a = m[c0 + i];
      o[i] = cur[i] * a + prev[i] * (1.f - a);
    }
    oa = *(float4*)&o[0]; ob = *(float4*)&o[4];
    *(short8*)(dst[which] + idx) = pack_bf8(oa, ob);
  }
}

// ---------------- ChannelMix token-shift mixes -> bf16 ----------------
__global__ __launch_bounds__(256) void mix_cm(const float* __restrict__ x2,
                                              const float* __restrict__ shift,
                                              const float* __restrict__ mk,
                                              const float* __restrict__ mr,
                                              unsigned short* __restrict__ xk2,
                                              unsigned short* __restrict__ xr2) {
  const int t = blockIdx.x;
  const int tid = threadIdx.x;
  const int c0 = tid * 8;
  const size_t idx = (size_t)t * C_DIM + c0;
  float cur[8], prev[8];
  *(float4*)&cur[0] = *(const float4*)(x2 + idx);
  *(float4*)&cur[4] = *(const float4*)(x2 + idx + 4);
  if (t == 0) {
    *(float4*)&prev[0] = *(const float4*)(shift + c0);
    *(float4*)&prev[4] = *(const float4*)(shift + c0 + 4);
  } else {
    *(float4*)&prev[0] = *(const float4*)(x2 + idx - C_DIM);
    *(float4*)&prev[4] = *(const float4*)(x2 + idx - C_DIM + 4);
  }
  float ok[8], orr[8];
#pragma unroll
  for (int i = 0; i < 8; ++i) {
    float a = mk[c0 + i];
    ok[i] = cur[i] * a + prev[i] * (1.f - a);
    a = mr[c0 + i];
    orr[i] = cur[i] * a + prev[i] * (1.f - a);
  }
  *(short8*)(xk2 + idx) = pack_bf8(*(float4*)&ok[0], *(float4*)&ok[4]);
  *(short8*)(xr2 + idx) = pack_bf8(*(float4*)&orr[0], *(float4*)&orr[4]);
}

// ======================= Chunk-parallel WKV v5 scan (f32) =======================
__global__ __launch_bounds__(256) void wkv_chunk_sum(const float* __restrict__ kin,
                                                     const float* __restrict__ vin,
                                                     const float* __restrict__ decay,
                                                     float* __restrict__ Abuf) {
  const int c = blockIdx.x, h = blockIdx.y;
  const int tid = threadIdx.x;
  const int vcol = tid >> 2, kg = tid & 3;
  __shared__ float ks[CHUNK][HS_DIM];
  __shared__ float vs[CHUNK][HS_DIM];
  for (int i = tid; i < CHUNK * HS_DIM / 4; i += 256) {
    int row = i >> 4, q = i & 15;
    size_t g = (size_t)(c * CHUNK + row) * C_DIM + h * HS_DIM + q * 4;
    *(float4*)&ks[row][q * 4] = *(const float4*)(kin + g);
    *(float4*)&vs[row][q * 4] = *(const float4*)(vin + g);
  }
  float w16[16], s[16];
#pragma unroll
  for (int j = 0; j < 16; ++j) {
    w16[j] = expf(-expf(decay[h * HS_DIM + kg * 16 + j]));
    s[j] = 0.f;
  }
  __syncthreads();
  for (int t = 0; t < CHUNK; ++t) {
    const float vt = vs[t][vcol];
    const float4* kp = (const float4*)&ks[t][kg * 16];
#pragma unroll
    for (int q = 0; q < 4; ++q) {
      float4 k4 = kp[q];
      s[q * 4 + 0] = __builtin_fmaf(s[q * 4 + 0], w16[q * 4 + 0], k4.x * vt);
      s[q * 4 + 1] = __builtin_fmaf(s[q * 4 + 1], w16[q * 4 + 1], k4.y * vt);
      s[q * 4 + 2] = __builtin_fmaf(s[q * 4 + 2], w16[q * 4 + 2], k4.z * vt);
      s[q * 4 + 3] = __builtin_fmaf(s[q * 4 + 3], w16[q * 4 + 3], k4.w * vt);
    }
  }
  const size_t base = (((size_t)h * NCHUNK + c) * HS_DIM + kg * 16) * HS_DIM + vcol;
#pragma unroll
  for (int j = 0; j < 16; ++j) Abuf[base + (size_t)j * HS_DIM] = s[j];
}

__global__ __launch_bounds__(256) void wkv_chain(const float* __restrict__ Abuf,
                                                 const float* __restrict__ s0,
                                                 const float* __restrict__ decay,
                                                 float* __restrict__ Sbuf) {
  const int h = blockIdx.x;
  const int tid = threadIdx.x;
  const int vcol = tid >> 2, kg = tid & 3;
  float wL[16], s[16];
#pragma unroll
  for (int j = 0; j < 16; ++j) {
    int kidx = kg * 16 + j;
    wL[j] = expf(-(float)CHUNK * expf(decay[h * HS_DIM + kidx]));
    s[j] = s0[((size_t)h * HS_DIM + kidx) * HS_DIM + vcol];
  }
  for (int c = 0; c < NCHUNK; ++c) {
    const size_t base = (((size_t)h * NCHUNK + c) * HS_DIM + kg * 16) * HS_DIM + vcol;
#pragma unroll
    for (int j = 0; j < 16; ++j) {
      Sbuf[base + (size_t)j * HS_DIM] = s[j];
      s[j] = __builtin_fmaf(s[j], wL[j], Abuf[base + (size_t)j * HS_DIM]);
    }
  }
}

__global__ __launch_bounds__(256) void wkv_chunk_out(const float* __restrict__ kin,
                                                     const float* __restrict__ vin,
                                                     const float* __restrict__ rin,
                                                     const float* __restrict__ decay,
                                                     const float* __restrict__ faaaa,
                                                     const float* __restrict__ Sbuf,
                                                     float* __restrict__ outp) {
  const int c = blockIdx.x, h = blockIdx.y;
  const int tid = threadIdx.x;
  const int vcol = tid >> 2, kg = tid & 3;
  __shared__ float ks[CHUNK][HS_DIM];
  __shared__ float rs[CHUNK][HS_DIM];
  __shared__ float vs[CHUNK][HS_DIM];
  for (int i = tid; i < CHUNK * HS_DIM / 4; i += 256) {
    int row = i >> 4, q = i & 15;
    size_t g = (size_t)(c * CHUNK + row) * C_DIM + h * HS_DIM + q * 4;
    *(float4*)&ks[row][q * 4] = *(const float4*)(kin + g);
    *(float4*)&rs[row][q * 4] = *(const float4*)(rin + g);
    *(float4*)&vs[row][q * 4] = *(const float4*)(vin + g);
  }
  float w16[16], u16[16], s[16];
  const size_t sbase = (((size_t)h * NCHUNK + c) * HS_DIM + kg * 16) * HS_DIM + vcol;
#pragma unroll
  for (int j = 0; j < 16; ++j) {
    int kidx = kg * 16 + j;
    w16[j] = expf(-expf(decay[h * HS_DIM + kidx]));
    u16[j] = faaaa[h * HS_DIM + kidx];
    s[j] = Sbuf[sbase + (size_t)j * HS_DIM];
  }
  __syncthreads();
  for (int t = 0; t < CHUNK; ++t) {
    const float vt = vs[t][vcol];
    const float4* kp = (const float4*)&ks[t][kg * 16];
    const float4* rp = (const float4*)&rs[t][kg * 16];
    float acc = 0.f, ruk = 0.f;
#pragma unroll
    for (int q = 0; q < 4; ++q) {
      float4 k4 = kp[q], r4 = rp[q];
      acc = __builtin_fmaf(r4.x, s[q * 4 + 0], acc);
      ruk = __builtin_fmaf(r4.x * u16[q * 4 + 0], k4.x, ruk);
      s[q * 4 + 0] = __builtin_fmaf(s[q * 4 + 0], w16[q * 4 + 0], k4.x * vt);
      acc = __builtin_fmaf(r4.y, s[q * 4 + 1], acc);
      ruk = __builtin_fmaf(r4.y * u16[q * 4 + 1], k4.y, ruk);
      s[q * 4 + 1] = __builtin_fmaf(s[q * 4 + 1], w16[q * 4 + 1], k4.y * vt);
      acc = __builtin_fmaf(r4.z, s[q * 4 + 2], acc);
      ruk = __builtin_fmaf(r4.z * u16[q * 4 + 2], k4.z, ruk);
      s[q * 4 + 2] = __builtin_fmaf(s[q * 4 + 2], w16[q * 4 + 2], k4.z * vt);
      acc = __builtin_fmaf(r4.w, s[q * 4 + 3], acc);
      ruk = __builtin_fmaf(r4.w * u16[q * 4 + 3], k4.w, ruk);
      s[q * 4 + 3] = __builtin_fmaf(s[q * 4 + 3], w16[q * 4 + 3], k4.w * vt);
    }
    float part = __builtin_fmaf(ruk, vt, acc);
    part += __shfl_xor(part, 1);
    part += __shfl_xor(part, 2);
    if (kg == 0) outp[(size_t)(c * CHUNK + t) * C_DIM + h * HS_DIM + vcol] = part;
  }
}

// ---------------- GroupNorm(out/8) * gn_w + gn_b, times silu(g) -> bf16 ----------------
__global__ __launch_bounds__(256) void gn_silu(const float* __restrict__ wkv,
                                               const float* __restrict__ gpre,
                                               const float* __restrict__ gw,
                                               const float* __restrict__ gb,
                                               unsigned short* __restrict__ zg) {
  const int idx = blockIdx.x * 4 + (threadIdx.x >> 6);  // group index = t*32 + h
  const int lane = threadIdx.x & 63;
  const int t = idx >> 5, h = idx & 31;
  const int c = h * HS_DIM + lane;
  const size_t off = (size_t)t * C_DIM + c;
  float z = wkv[off] * 0.125f;
  float s = z, sq = z * z;
#pragma unroll
  for (int o = 1; o < 64; o <<= 1) { s += __shfl_xor(s, o); sq += __shfl_xor(sq, o); }
  const float mean = s * (1.f / HS_DIM);
  const float var = sq * (1.f / HS_DIM) - mean * mean;
  const float val = (z - mean) * rsqrtf(var + 1e-5f) * gw[c] + gb[c];
  const float g = gpre[off];
  const float sig = 1.f / (1.f + __expf(-g));
  zg[off] = f2bf(val * (g * sig));
}

// ---------------- bf16 GEMM: C[M,N] = A[M,K] * B[N,K]^T, global_load_lds staging ----------------
struct GemmBatch {
  const unsigned short* A[4];
  const unsigned short* B[4];
  void* C[4];
  const float* E0[4];
  const float* E1[4];
};

// EPI: 0 = f32 C=acc; 1 = f32 C=acc+E0; 2 = bf16 C=relu(acc)^2; 3 = f32 C=E1+sigmoid(E0)*acc
template <int EPI, int BM>
__global__ __launch_bounds__(256) void gemm_lds(GemmBatch gb, int M, int N, int K) {
  constexpr int FM = BM / 32;  // frags per wave in M (wave grid 2x2, wave tile (FM*16) x 64)
  const int zb = blockIdx.z;
  const unsigned short* __restrict__ A = gb.A[zb];
  const unsigned short* __restrict__ B = gb.B[zb];
  const float* __restrict__ E0 = gb.E0[zb];
  const float* __restrict__ E1 = gb.E1[zb];

  __shared__ unsigned short As[BM * 32];
  __shared__ unsigned short Bs[128 * 32];

  const int tid = threadIdx.x;
  const int l = tid & 63;
  const int w = tid >> 6;
  const int wm = w >> 1, wn = w & 1;
  const int m0 = blockIdx.y * BM, n0 = blockIdx.x * 128;
  const int lrow = l & 15;
  const int koff = (l >> 4) * 8;

  // staging: per issue, wave w covers rows [i*64 + w*16, +16), lane l -> row + l/4, bytes (l&3)*16
  const int srow = w * 16 + (l >> 2);
  const int scb = (l & 3) * 16;
  const char* Ag = (const char*)A + ((size_t)(m0 + srow) * K) * 2 + scb;
  const char* Bg = (const char*)B + ((size_t)(n0 + srow) * K) * 2 + scb;
  char* Asl = (char*)As + w * 1024;  // + i*4096
  char* Bsl = (char*)Bs + w * 1024;

  f32x4 acc[FM][4];
#pragma unroll
  for (int m = 0; m < FM; ++m)
#pragma unroll
    for (int n = 0; n < 4; ++n) acc[m][n] = (f32x4){0.f, 0.f, 0.f, 0.f};

  for (int kk = 0; kk < K; kk += 32) {
#pragma unroll
    for (int i = 0; i < BM / 64; ++i)
      gl_lds16(Ag + ((size_t)(i * 64) * K + kk) * 2, Asl + i * 4096);
#pragma unroll
    for (int i = 0; i < 2; ++i)
      gl_lds16(Bg + ((size_t)(i * 64) * K + kk) * 2, Bsl + i * 4096);
    __syncthreads();
    short8 af[FM], bf[4];
#pragma unroll
    for (int m = 0; m < FM; ++m)
      af[m] = *(const short8*)&As[(wm * (FM * 16) + m * 16 + lrow) * 32 + koff];
#pragma unroll
    for (int n = 0; n < 4; ++n)
      bf[n] = *(const short8*)&Bs[(wn * 64 + n * 16 + lrow) * 32 + koff];
#pragma unroll
    for (int m = 0; m < FM; ++m)
#pragma unroll
      for (int n = 0; n < 4; ++n)
        acc[m][n] = __builtin_amdgcn_mfma_f32_16x16x32_bf16(af[m], bf[n], acc[m][n], 0, 0, 0);
    __syncthreads();
  }

#pragma unroll
  for (int m = 0; m < FM; ++m) {
#pragma unroll
    for (int n = 0; n < 4; ++n) {
#pragma unroll
      for (int j = 0; j < 4; ++j) {
        int row = m0 + wm * (FM * 16) + m * 16 + ((l >> 4) << 2) + j;
        int col = n0 + wn * 64 + n * 16 + lrow;
        size_t idx = (size_t)row * N + col;
        float v = acc[m][n][j];
        if (EPI == 2) {
          float tpos = v > 0.f ? v : 0.f;
          ((unsigned short*)gb.C[zb])[idx] = f2bf(tpos * tpos);
        } else {
          if (EPI == 1) {
            v += E0[idx];
          } else if (EPI == 3) {
            float sg = 1.f / (1.f + __expf(-E0[idx]));
            v = E1[idx] + sg * v;
          }
          ((float*)gb.C[zb])[idx] = v;
        }
      }
    }
  }
}

extern "C" void kernel_launch(void* const* d_in, const int* in_sizes, int n_in,
                              void* d_out, int out_size, void* d_ws, size_t ws_size,
                              hipStream_t stream) {
  (void)in_sizes; (void)n_in; (void)out_size; (void)ws_size;
  const float* x         = (const float*)d_in[0];
  const float* att_shift = (const float*)d_in[1];
  const float* wkv_state = (const float*)d_in[2];
  const float* ffn_shift = (const float*)d_in[3];
  const float* ln1_w = (const float*)d_in[4];
  const float* ln1_b = (const float*)d_in[5];
  const float* ln2_w = (const float*)d_in[6];
  const float* ln2_b = (const float*)d_in[7];
  const float* tm_k = (const float*)d_in[8];
  const float* tm_v = (const float*)d_in[9];
  const float* tm_r = (const float*)d_in[10];
  const float* tm_g = (const float*)d_in[11];
  const float* time_decay = (const float*)d_in[12];
  const float* time_faaaa = (const float*)d_in[13];
  const float* Wr = (const float*)d_in[14];
  const float* Wk = (const float*)d_in[15];
  const float* Wv = (const float*)d_in[16];
  const float* Wo = (const float*)d_in[17];
  const float* Wg = (const float*)d_in[18];
  const float* gn_w = (const float*)d_in[19];
  const float* gn_b = (const float*)d_in[20];
  const float* cm_k = (const float*)d_in[21];
  const float* cm_r = (const float*)d_in[22];
  const float* Wck = (const float*)d_in[23];
  const float* Wcr = (const float*)d_in[24];
  const float* Wcv = (const float*)d_in[25];
  float* out = (float*)d_out;

  char* ws = (char*)d_ws;
  const size_t CC2 = (size_t)C_DIM * C_DIM * 2;          // 8,388,608
  const size_t FFC2 = (size_t)FF_DIM * C_DIM * 2;        // 29,360,128
  unsigned short* Wr_b  = (unsigned short*)(ws + 0 * CC2);
  unsigned short* Wk_b  = (unsigned short*)(ws + 1 * CC2);
  unsigned short* Wv_b  = (unsigned short*)(ws + 2 * CC2);
  unsigned short* Wg_b  = (unsigned short*)(ws + 3 * CC2);
  unsigned short* Wo_b  = (unsigned short*)(ws + 4 * CC2);
  unsigned short* Wcr_b = (unsigned short*)(ws + 5 * CC2);
  unsigned short* Wck_b = (unsigned short*)(ws + 6 * CC2);
  unsigned short* Wcv_b = (unsigned short*)(ws + 6 * CC2 + FFC2);
  char* act = ws + 6 * CC2 + 2 * FFC2;                   // 109,051,904

  const size_t RF = (size_t)T_LEN * C_DIM * 4;           // 8,388,608 (f32 region)
  const size_t RB = (size_t)T_LEN * C_DIM * 2;           // 4,194,304 (bf16 region)
  float*          x1   = (float*)(act);                  // alias: wkvo
  unsigned short* xr_b = (unsigned short*)(act + RF);            // alias: Abuf (xr+xk)
  unsigned short* xk_b = (unsigned short*)(act + RF + RB);
  unsigned short* xv_b = (unsigned short*)(act + RF + 2 * RB);   // alias: Sbuf (xv+xg)
  unsigned short* xg_b = (unsigned short*)(act + RF + 3 * RB);
  float*          rb   = (float*)(act + RF + 4 * RB);            // alias: x2
  float*          kb   = (float*)(act + 2 * RF + 4 * RB);        // alias: xk2_b,xr2_b
  float*          vb   = (float*)(act + 3 * RF + 4 * RB);        // alias: kk_b (vb+gpre)
  float*          gpre = (float*)(act + 4 * RF + 4 * RB);
  unsigned short* zg_b = (unsigned short*)(act + 5 * RF + 4 * RB);
  float*          xnew = (float*)(act + 5 * RF + 5 * RB);
  float*          s1   = (float*)(act + 6 * RF + 5 * RB);
  // aliases
  float*          wkvo  = x1;
  float*          Abuf  = (float*)xr_b;
  float*          Sbuf  = (float*)xv_b;
  float*          x2    = rb;
  unsigned short* xk2_b = (unsigned short*)kb;
  unsigned short* xr2_b = (unsigned short*)((char*)kb + RB);
  unsigned short* kk_b  = (unsigned short*)vb;

  dim3 blk(256);
  const int CCn8 = C_DIM * C_DIM / 8;
  const int FFn8 = FF_DIM * C_DIM / 8;

  // --- weight conversion (independent of everything else) ---
  cvt_bf16<<<2048, blk, 0, stream>>>(Wr, Wr_b, CCn8);
  cvt_bf16<<<2048, blk, 0, stream>>>(Wk, Wk_b, CCn8);
  cvt_bf16<<<2048, blk, 0, stream>>>(Wv, Wv_b, CCn8);
  cvt_bf16<<<2048, blk, 0, stream>>>(Wg, Wg_b, CCn8);
  cvt_bf16<<<2048, blk, 0, stream>>>(Wo, Wo_b, CCn8);
  cvt_bf16<<<2048, blk, 0, stream>>>(Wcr, Wcr_b, CCn8);
  cvt_bf16<<<2048, blk, 0, stream>>>(Wck, Wck_b, FFn8);
  cvt_bf16<<<2048, blk, 0, stream>>>(Wcv, Wcv_b, FFn8);

  // --- TimeMix ---
  ln_kernel<<<T_LEN, blk, 0, stream>>>(x, ln1_w, ln1_b, x1);
  mix_att<<<T_LEN, blk, 0, stream>>>(x1, att_shift, tm_r, tm_k, tm_v, tm_g,
                                     xr_b, xk_b, xv_b, xg_b);
  GemmBatch g4 = {};
  g4.A[0] = xr_b; g4.B[0] = Wr_b; g4.C[0] = rb;
  g4.A[1] = xk_b; g4.B[1] = Wk_b; g4.C[1] = kb;
  g4.A[2] = xv_b; g4.B[2] = Wv_b; g4.C[2] = vb;
  g4.A[3] = xg_b; g4.B[3] = Wg_b; g4.C[3] = gpre;
  gemm_lds<0, 128><<<dim3(16, 8, 4), blk, 0, stream>>>(g4, T_LEN, C_DIM, C_DIM);

  // chunk-parallel WKV scan (f32)
  wkv_chunk_sum<<<dim3(NCHUNK, H_NUM), blk, 0, stream>>>(kb, vb, time_decay, Abuf);
  wkv_chain<<<H_NUM, blk, 0, stream>>>(Abuf, wkv_state, time_decay, Sbuf);
  wkv_chunk_out<<<dim3(NCHUNK, H_NUM), blk, 0, stream>>>(kb, vb, rb, time_decay, time_faaaa,
                                                         Sbuf, wkvo);

  gn_silu<<<(T_LEN * H_NUM) / 4, blk, 0, stream>>>(wkvo, gpre, gn_w, gn_b, zg_b);
  GemmBatch go = {};
  go.A[0] = zg_b; go.B[0] = Wo_b; go.C[0] = xnew; go.E0[0] = x;
  gemm_lds<1, 64><<<dim3(16, 16, 1), blk, 0, stream>>>(go, T_LEN, C_DIM, C_DIM);

  // --- ChannelMix ---
  ln_kernel<<<T_LEN, blk, 0, stream>>>(xnew, ln2_w, ln2_b, x2);
  mix_cm<<<T_LEN, blk, 0, stream>>>(x2, ffn_shift, cm_k, cm_r, xk2_b, xr2_b);
  GemmBatch gk = {};
  gk.A[0] = xk2_b; gk.B[0] = Wck_b; gk.C[0] = kk_b;
  gemm_lds<2, 128><<<dim3(56, 8, 1), blk, 0, stream>>>(gk, T_LEN, FF_DIM, C_DIM);
  GemmBatch gr = {};
  gr.A[0] = xr2_b; gr.B[0] = Wcr_b; gr.C[0] = s1;
  gemm_lds<0, 64><<<dim3(16, 16, 1), blk, 0, stream>>>(gr, T_LEN, C_DIM, C_DIM);
  GemmBatch gv = {};
  gv.A[0] = kk_b; gv.B[0] = Wcv_b; gv.C[0] = out; gv.E0[0] = s1; gv.E1[0] = xnew;
  gemm_lds<3, 64><<<dim3(16, 16, 1), blk, 0, stream>>>(gv, T_LEN, C_DIM, FF_DIM);
}

// Round 4
// 410.439 us; speedup vs baseline: 3.3944x; 1.2113x over previous
//
#include <hip/hip_runtime.h>

#define T_LEN 1024
#define C_DIM 2048
#define H_NUM 32
#define HS_DIM 64
#define FF_DIM 7168
#define CHUNK 64
#define NCHUNK (T_LEN / CHUNK)

typedef __attribute__((ext_vector_type(4))) float f32x4;
typedef __attribute__((ext_vector_type(8))) short short8;

__device__ __forceinline__ unsigned short f2bf(float f) {
  unsigned int u = __float_as_uint(f);
  unsigned int r = (u + 0x7FFFu + ((u >> 16) & 1u)) >> 16;
  return (unsigned short)r;
}

__device__ __forceinline__ short8 pack_bf8(float4 a, float4 b) {
  short8 o;
  o[0] = (short)f2bf(a.x); o[1] = (short)f2bf(a.y);
  o[2] = (short)f2bf(a.z); o[3] = (short)f2bf(a.w);
  o[4] = (short)f2bf(b.x); o[5] = (short)f2bf(b.y);
  o[6] = (short)f2bf(b.z); o[7] = (short)f2bf(b.w);
  return o;
}

__device__ __forceinline__ void gl_lds16(const void* g, void* l) {
  __builtin_amdgcn_global_load_lds(
      (const __attribute__((address_space(1))) unsigned int*)g,
      (__attribute__((address_space(3))) unsigned int*)l, 16, 0, 0);
}

// ---------------- f32 -> bf16 convert, all 8 weights in one launch ----------------
struct Cvt8 {
  const float* s[8];
  unsigned short* d[8];
  int n8[8];
};

__global__ __launch_bounds__(256) void cvt_all(Cvt8 cv) {
  const int y = blockIdx.y;
  const float* s = cv.s[y];
  unsigned short* d = cv.d[y];
  const int n8 = cv.n8[y];
  for (int i = blockIdx.x * 256 + threadIdx.x; i < n8; i += gridDim.x * 256) {
    const float4* p = (const float4*)(s + (size_t)i * 8);
    *(short8*)(d + (size_t)i * 8) = pack_bf8(p[0], p[1]);
  }
}

// ---------------- LayerNorm over C=2048, one block per token ----------------
__global__ __launch_bounds__(256) void ln_kernel(const float* __restrict__ x,
                                                 const float* __restrict__ w,
                                                 const float* __restrict__ b,
                                                 float* __restrict__ out) {
  const int t = blockIdx.x;
  const int tid = threadIdx.x;
  const float* xr = x + (size_t)t * C_DIM;
  float4 v1 = *(const float4*)(xr + tid * 8);
  float4 v2 = *(const float4*)(xr + tid * 8 + 4);
  float vals[8] = {v1.x, v1.y, v1.z, v1.w, v2.x, v2.y, v2.z, v2.w};
  float s = 0.f, sq = 0.f;
#pragma unroll
  for (int i = 0; i < 8; ++i) { s += vals[i]; sq = __builtin_fmaf(vals[i], vals[i], sq); }
#pragma unroll
  for (int o = 1; o < 64; o <<= 1) { s += __shfl_xor(s, o); sq += __shfl_xor(sq, o); }
  __shared__ float red[8];
  const int wave = tid >> 6, lane = tid & 63;
  if (lane == 0) { red[wave] = s; red[4 + wave] = sq; }
  __syncthreads();
  s = red[0] + red[1] + red[2] + red[3];
  sq = red[4] + red[5] + red[6] + red[7];
  const float mean = s * (1.f / C_DIM);
  const float var = sq * (1.f / C_DIM) - mean * mean;
  const float inv = rsqrtf(var + 1e-5f);
  float* orow = out + (size_t)t * C_DIM;
#pragma unroll
  for (int i = 0; i < 8; ++i) {
    int c = tid * 8 + i;
    orow[c] = (vals[i] - mean) * inv * w[c] + b[c];
  }
}

// ---------------- TimeMix token-shift mixes -> bf16 ----------------
__global__ __launch_bounds__(256) void mix_att(const float* __restrict__ x1,
                                               const float* __restrict__ shift,
                                               const float* __restrict__ mr,
                                               const float* __restrict__ mk,
                                               const float* __restrict__ mv,
                                               const float* __restrict__ mg,
                                               unsigned short* __restrict__ xr,
                                               unsigned short* __restrict__ xk,
                                               unsigned short* __restrict__ xv,
                                               unsigned short* __restrict__ xg) {
  const int t = blockIdx.x;
  const int tid = threadIdx.x;
  const int c0 = tid * 8;
  const size_t idx = (size_t)t * C_DIM + c0;
  float cur[8], prev[8];
  *(float4*)&cur[0] = *(const float4*)(x1 + idx);
  *(float4*)&cur[4] = *(const float4*)(x1 + idx + 4);
  if (t == 0) {
    *(float4*)&prev[0] = *(const float4*)(shift + c0);
    *(float4*)&prev[4] = *(const float4*)(shift + c0 + 4);
  } else {
    *(float4*)&prev[0] = *(const float4*)(x1 + idx - C_DIM);
    *(float4*)&prev[4] = *(const float4*)(x1 + idx - C_DIM + 4);
  }
  const float* mix[4] = {mr, mk, mv, mg};
  unsigned short* dst[4] = {xr, xk, xv, xg};
#pragma unroll
  for (int which = 0; which < 4; ++which) {
    const float* m = mix[which];
    float o[8];
#pragma unroll
    for (int i = 0; i < 8; ++i) {
      float a = m[c0 + i];
      o[i] = cur[i] * a + prev[i] * (1.f - a);
    }
    *(short8*)(dst[which] + idx) = pack_bf8(*(float4*)&o[0], *(float4*)&o[4]);
  }
}

// ---------------- ChannelMix token-shift mixes -> bf16 ----------------
__global__ __launch_bounds__(256) void mix_cm(const float* __restrict__ x2,
                                              const float* __restrict__ shift,
                                              const float* __restrict__ mk,
                                              const float* __restrict__ mr,
                                              unsigned short* __restrict__ xk2,
                                              unsigned short* __restrict__ xr2) {
  const int t = blockIdx.x;
  const int tid = threadIdx.x;
  const int c0 = tid * 8;
  const size_t idx = (size_t)t * C_DIM + c0;
  float cur[8], prev[8];
  *(float4*)&cur[0] = *(const float4*)(x2 + idx);
  *(float4*)&cur[4] = *(const float4*)(x2 + idx + 4);
  if (t == 0) {
    *(float4*)&prev[0] = *(const float4*)(shift + c0);
    *(float4*)&prev[4] = *(const float4*)(shift + c0 + 4);
  } else {
    *(float4*)&prev[0] = *(const float4*)(x2 + idx - C_DIM);
    *(float4*)&prev[4] = *(const float4*)(x2 + idx - C_DIM + 4);
  }
  float ok[8], orr[8];
#pragma unroll
  for (int i = 0; i < 8; ++i) {
    float a = mk[c0 + i];
    ok[i] = cur[i] * a + prev[i] * (1.f - a);
    a = mr[c0 + i];
    orr[i] = cur[i] * a + prev[i] * (1.f - a);
  }
  *(short8*)(xk2 + idx) = pack_bf8(*(float4*)&ok[0], *(float4*)&ok[4]);
  *(short8*)(xr2 + idx) = pack_bf8(*(float4*)&orr[0], *(float4*)&orr[4]);
}

// ======================= Chunk-parallel WKV v5 scan (f32) =======================
__global__ __launch_bounds__(256) void wkv_chunk_sum(const float* __restrict__ kin,
                                                     const float* __restrict__ vin,
                                                     const float* __restrict__ decay,
                                                     float* __restrict__ Abuf) {
  const int c = blockIdx.x, h = blockIdx.y;
  const int tid = threadIdx.x;
  const int vcol = tid >> 2, kg = tid & 3;
  __shared__ float ks[CHUNK][HS_DIM];
  __shared__ float vs[CHUNK][HS_DIM];
  for (int i = tid; i < CHUNK * HS_DIM / 4; i += 256) {
    int row = i >> 4, q = i & 15;
    size_t g = (size_t)(c * CHUNK + row) * C_DIM + h * HS_DIM + q * 4;
    *(float4*)&ks[row][q * 4] = *(const float4*)(kin + g);
    *(float4*)&vs[row][q * 4] = *(const float4*)(vin + g);
  }
  float w16[16], s[16];
#pragma unroll
  for (int j = 0; j < 16; ++j) {
    w16[j] = expf(-expf(decay[h * HS_DIM + kg * 16 + j]));
    s[j] = 0.f;
  }
  __syncthreads();
  for (int t = 0; t < CHUNK; ++t) {
    const float vt = vs[t][vcol];
    const float4* kp = (const float4*)&ks[t][kg * 16];
#pragma unroll
    for (int q = 0; q < 4; ++q) {
      float4 k4 = kp[q];
      s[q * 4 + 0] = __builtin_fmaf(s[q * 4 + 0], w16[q * 4 + 0], k4.x * vt);
      s[q * 4 + 1] = __builtin_fmaf(s[q * 4 + 1], w16[q * 4 + 1], k4.y * vt);
      s[q * 4 + 2] = __builtin_fmaf(s[q * 4 + 2], w16[q * 4 + 2], k4.z * vt);
      s[q * 4 + 3] = __builtin_fmaf(s[q * 4 + 3], w16[q * 4 + 3], k4.w * vt);
    }
  }
  const size_t base = (((size_t)h * NCHUNK + c) * HS_DIM + kg * 16) * HS_DIM + vcol;
#pragma unroll
  for (int j = 0; j < 16; ++j) Abuf[base + (size_t)j * HS_DIM] = s[j];
}

__global__ __launch_bounds__(256) void wkv_chain(const float* __restrict__ Abuf,
                                                 const float* __restrict__ s0,
                                                 const float* __restrict__ decay,
                                                 float* __restrict__ Sbuf) {
  const int h = blockIdx.x;
  const int tid = threadIdx.x;
  const int vcol = tid >> 2, kg = tid & 3;
  float wL[16], s[16];
#pragma unroll
  for (int j = 0; j < 16; ++j) {
    int kidx = kg * 16 + j;
    wL[j] = expf(-(float)CHUNK * expf(decay[h * HS_DIM + kidx]));
    s[j] = s0[((size_t)h * HS_DIM + kidx) * HS_DIM + vcol];
  }
  for (int c = 0; c < NCHUNK; ++c) {
    const size_t base = (((size_t)h * NCHUNK + c) * HS_DIM + kg * 16) * HS_DIM + vcol;
#pragma unroll
    for (int j = 0; j < 16; ++j) {
      Sbuf[base + (size_t)j * HS_DIM] = s[j];
      s[j] = __builtin_fmaf(s[j], wL[j], Abuf[base + (size_t)j * HS_DIM]);
    }
  }
}

__global__ __launch_bounds__(256) void wkv_chunk_out(const float* __restrict__ kin,
                                                     const float* __restrict__ vin,
                                                     const float* __restrict__ rin,
                                                     const float* __restrict__ decay,
                                                     const float* __restrict__ faaaa,
                                                     const float* __restrict__ Sbuf,
                                                     float* __restrict__ outp) {
  const int c = blockIdx.x, h = blockIdx.y;
  const int tid = threadIdx.x;
  const int vcol = tid >> 2, kg = tid & 3;
  __shared__ float ks[CHUNK][HS_DIM];
  __shared__ float rs[CHUNK][HS_DIM];
  __shared__ float vs[CHUNK][HS_DIM];
  for (int i = tid; i < CHUNK * HS_DIM / 4; i += 256) {
    int row = i >> 4, q = i & 15;
    size_t g = (size_t)(c * CHUNK + row) * C_DIM + h * HS_DIM + q * 4;
    *(float4*)&ks[row][q * 4] = *(const float4*)(kin + g);
    *(float4*)&rs[row][q * 4] = *(const float4*)(rin + g);
    *(float4*)&vs[row][q * 4] = *(const float4*)(vin + g);
  }
  float w16[16], u16[16], s[16];
  const size_t sbase = (((size_t)h * NCHUNK + c) * HS_DIM + kg * 16) * HS_DIM + vcol;
#pragma unroll
  for (int j = 0; j < 16; ++j) {
    int kidx = kg * 16 + j;
    w16[j] = expf(-expf(decay[h * HS_DIM + kidx]));
    u16[j] = faaaa[h * HS_DIM + kidx];
    s[j] = Sbuf[sbase + (size_t)j * HS_DIM];
  }
  __syncthreads();
  for (int t = 0; t < CHUNK; ++t) {
    const float vt = vs[t][vcol];
    const float4* kp = (const float4*)&ks[t][kg * 16];
    const float4* rp = (const float4*)&rs[t][kg * 16];
    float acc = 0.f, ruk = 0.f;
#pragma unroll
    for (int q = 0; q < 4; ++q) {
      float4 k4 = kp[q], r4 = rp[q];
      acc = __builtin_fmaf(r4.x, s[q * 4 + 0], acc);
      ruk = __builtin_fmaf(r4.x * u16[q * 4 + 0], k4.x, ruk);
      s[q * 4 + 0] = __builtin_fmaf(s[q * 4 + 0], w16[q * 4 + 0], k4.x * vt);
      acc = __builtin_fmaf(r4.y, s[q * 4 + 1], acc);
      ruk = __builtin_fmaf(r4.y * u16[q * 4 + 1], k4.y, ruk);
      s[q * 4 + 1] = __builtin_fmaf(s[q * 4 + 1], w16[q * 4 + 1], k4.y * vt);
      acc = __builtin_fmaf(r4.z, s[q * 4 + 2], acc);
      ruk = __builtin_fmaf(r4.z * u16[q * 4 + 2], k4.z, ruk);
      s[q * 4 + 2] = __builtin_fmaf(s[q * 4 + 2], w16[q * 4 + 2], k4.z * vt);
      acc = __builtin_fmaf(r4.w, s[q * 4 + 3], acc);
      ruk = __builtin_fmaf(r4.w * u16[q * 4 + 3], k4.w, ruk);
      s[q * 4 + 3] = __builtin_fmaf(s[q * 4 + 3], w16[q * 4 + 3], k4.w * vt);
    }
    float part = __builtin_fmaf(ruk, vt, acc);
    part += __shfl_xor(part, 1);
    part += __shfl_xor(part, 2);
    if (kg == 0) outp[(size_t)(c * CHUNK + t) * C_DIM + h * HS_DIM + vcol] = part;
  }
}

// ---------------- GroupNorm(out/8) * gn_w + gn_b, times silu(g) -> bf16 ----------------
__global__ __launch_bounds__(256) void gn_silu(const float* __restrict__ wkv,
                                               const float* __restrict__ gpre,
                                               const float* __restrict__ gw,
                                               const float* __restrict__ gb,
                                               unsigned short* __restrict__ zg) {
  const int idx = blockIdx.x * 4 + (threadIdx.x >> 6);  // group index = t*32 + h
  const int lane = threadIdx.x & 63;
  const int t = idx >> 5, h = idx & 31;
  const int c = h * HS_DIM + lane;
  const size_t off = (size_t)t * C_DIM + c;
  float z = wkv[off] * 0.125f;
  float s = z, sq = z * z;
#pragma unroll
  for (int o = 1; o < 64; o <<= 1) { s += __shfl_xor(s, o); sq += __shfl_xor(sq, o); }
  const float mean = s * (1.f / HS_DIM);
  const float var = sq * (1.f / HS_DIM) - mean * mean;
  const float val = (z - mean) * rsqrtf(var + 1e-5f) * gw[c] + gb[c];
  const float g = gpre[off];
  const float sig = 1.f / (1.f + __expf(-g));
  zg[off] = f2bf(val * (g * sig));
}

// ============== bf16 GEMM, BM=64 BN=128 BK=64, dbuf LDS + XOR swizzle ==============
// C[M,N] = A[M,K] * B[N,K]^T.  EPI: 0 = f32 raw; 2 = bf16 relu(acc)^2.
// SPLITK>1: blockIdx.z = batch*SPLITK + s; split 0 writes raw f32 C, splits >=1
// write raw f32 partials to P + (s-1)*M*N. Epilogue applied by reduce kernels.
struct GemmBatch {
  const unsigned short* A[4];
  const unsigned short* B[4];
  void* C[4];
};

template <int EPI, int SPLITK>
__global__ __launch_bounds__(256) void gemm64(GemmBatch gb, int M, int N, int K,
                                              float* __restrict__ P) {
  const int zz = blockIdx.z;
  const int s = zz % SPLITK, zb = zz / SPLITK;
  const int Ks = K / SPLITK;
  const int k0 = s * Ks;
  const unsigned short* __restrict__ A = gb.A[zb];
  const unsigned short* __restrict__ B = gb.B[zb];

  __shared__ unsigned short As[2][64 * 64];   // 8 KB each
  __shared__ unsigned short Bs[2][128 * 64];  // 16 KB each

  const int tid = threadIdx.x;
  const int l = tid & 63;
  const int w = tid >> 6;
  const int wm = w >> 1, wn = w & 1;
  const int m0 = blockIdx.y * 64, n0 = blockIdx.x * 128;
  const int lrow = l & 15;

  // staging lane geometry: 8 rows x 128B per wave-issue; global col slot XOR-swizzled
  const int r8 = l >> 3;
  const int swz = ((l & 7) ^ r8) * 16;
  const char* Agl = (const char*)A + ((size_t)(m0 + w * 16 + r8) * K) * 2 + swz;
  const char* Bgl = (const char*)B + ((size_t)(n0 + w * 32 + r8) * K) * 2 + swz;

  f32x4 acc[2][4];
#pragma unroll
  for (int m = 0; m < 2; ++m)
#pragma unroll
    for (int n = 0; n < 4; ++n) acc[m][n] = (f32x4){0.f, 0.f, 0.f, 0.f};

  const size_t Kb = (size_t)K * 2;

#define STAGE(buf, kk)                                                         \
  {                                                                            \
    const size_t kb2 = (size_t)(kk) * 2;                                       \
    _Pragma("unroll") for (int i = 0; i < 2; ++i)                              \
        gl_lds16(Agl + (size_t)(i * 8) * Kb + kb2,                             \
                 &As[buf][(w * 16 + i * 8) * 64]);                             \
    _Pragma("unroll") for (int i = 0; i < 4; ++i)                              \
        gl_lds16(Bgl + (size_t)(i * 8) * Kb + kb2,                             \
                 &Bs[buf][(w * 32 + i * 8) * 64]);                             \
  }

  STAGE(0, k0);
  __syncthreads();

  const int nt = Ks / 64;
  for (int t = 0; t < nt; ++t) {
    const int buf = t & 1;
    if (t + 1 < nt) STAGE(buf ^ 1, k0 + (t + 1) * 64);
    const char* Ab = (const char*)&As[buf][0];
    const char* Bb = (const char*)&Bs[buf][0];
    short8 af[2][2], bfr[2][4];
#pragma unroll
    for (int ks = 0; ks < 2; ++ks) {
      const int kb = ks * 64 + ((l >> 4) * 16);
#pragma unroll
      for (int m = 0; m < 2; ++m) {
        const int row = wm * 32 + m * 16 + lrow;
        af[ks][m] = *(const short8*)(Ab + row * 128 + (kb ^ ((row & 7) << 4)));
      }
#pragma unroll
      for (int n = 0; n < 4; ++n) {
        const int row = wn * 64 + n * 16 + lrow;
        bfr[ks][n] = *(const short8*)(Bb + row * 128 + (kb ^ ((row & 7) << 4)));
      }
    }
#pragma unroll
    for (int ks = 0; ks < 2; ++ks)
#pragma unroll
      for (int m = 0; m < 2; ++m)
#pragma unroll
        for (int n = 0; n < 4; ++n)
          acc[m][n] =
              __builtin_amdgcn_mfma_f32_16x16x32_bf16(af[ks][m], bfr[ks][n], acc[m][n], 0, 0, 0);
    __syncthreads();
  }
#undef STAGE

  float* Co;
  if (SPLITK > 1)
    Co = (s == 0) ? (float*)gb.C[zb] : P + (size_t)(s - 1) * M * N;
  else
    Co = (float*)gb.C[zb];

#pragma unroll
  for (int m = 0; m < 2; ++m) {
#pragma unroll
    for (int n = 0; n < 4; ++n) {
#pragma unroll
      for (int j = 0; j < 4; ++j) {
        const int row = m0 + wm * 32 + m * 16 + ((l >> 4) << 2) + j;
        const int col = n0 + wn * 64 + n * 16 + lrow;
        const size_t idx = (size_t)row * N + col;
        const float v = acc[m][n][j];
        if (EPI == 2 && SPLITK == 1) {
          float tpos = v > 0.f ? v : 0.f;
          ((unsigned short*)gb.C[zb])[idx] = f2bf(tpos * tpos);
        } else {
          Co[idx] = v;
        }
      }
    }
  }
}

// ---------------- split-K reduce + fused epilogues ----------------
// MODE 0: C += P ; MODE 1: C += P + E0 ; MODE 3: C = E1 + sig(E0)*(C+P0+P1+P2)
template <int MODE>
__global__ __launch_bounds__(256) void reduce_k(float* __restrict__ C,
                                                const float* __restrict__ P,
                                                const float* __restrict__ E0,
                                                const float* __restrict__ E1,
                                                size_t n4) {
  for (size_t i = (size_t)blockIdx.x * 256 + threadIdx.x; i < n4;
       i += (size_t)gridDim.x * 256) {
    float4 c = ((const float4*)C)[i];
    float4 p = ((const float4*)P)[i];
    if (MODE == 0) {
      c.x += p.x; c.y += p.y; c.z += p.z; c.w += p.w;
    } else if (MODE == 1) {
      float4 e = ((const float4*)E0)[i];
      c.x += p.x + e.x; c.y += p.y + e.y; c.z += p.z + e.z; c.w += p.w + e.w;
    } else {
      float4 p1 = ((const float4*)P)[i + n4];
      float4 p2 = ((const float4*)P)[i + 2 * n4];
      float4 e0 = ((const float4*)E0)[i];
      float4 e1 = ((const float4*)E1)[i];
      c.x = e1.x + (1.f / (1.f + __expf(-e0.x))) * (c.x + p.x + p1.x + p2.x);
      c.y = e1.y + (1.f / (1.f + __expf(-e0.y))) * (c.y + p.y + p1.y + p2.y);
      c.z = e1.z + (1.f / (1.f + __expf(-e0.z))) * (c.z + p.z + p1.z + p2.z);
      c.w = e1.w + (1.f / (1.f + __expf(-e0.w))) * (c.w + p.w + p1.w + p2.w);
    }
    ((float4*)C)[i] = c;
  }
}

extern "C" void kernel_launch(void* const* d_in, const int* in_sizes, int n_in,
                              void* d_out, int out_size, void* d_ws, size_t ws_size,
                              hipStream_t stream) {
  (void)in_sizes; (void)n_in; (void)out_size; (void)ws_size;
  const float* x         = (const float*)d_in[0];
  const float* att_shift = (const float*)d_in[1];
  const float* wkv_state = (const float*)d_in[2];
  const float* ffn_shift = (const float*)d_in[3];
  const float* ln1_w = (const float*)d_in[4];
  const float* ln1_b = (const float*)d_in[5];
  const float* ln2_w = (const float*)d_in[6];
  const float* ln2_b = (const float*)d_in[7];
  const float* tm_k = (const float*)d_in[8];
  const float* tm_v = (const float*)d_in[9];
  const float* tm_r = (const float*)d_in[10];
  const float* tm_g = (const float*)d_in[11];
  const float* time_decay = (const float*)d_in[12];
  const float* time_faaaa = (const float*)d_in[13];
  const float* Wr = (const float*)d_in[14];
  const float* Wk = (const float*)d_in[15];
  const float* Wv = (const float*)d_in[16];
  const float* Wo = (const float*)d_in[17];
  const float* Wg = (const float*)d_in[18];
  const float* gn_w = (const float*)d_in[19];
  const float* gn_b = (const float*)d_in[20];
  const float* cm_k = (const float*)d_in[21];
  const float* cm_r = (const float*)d_in[22];
  const float* Wck = (const float*)d_in[23];
  const float* Wcr = (const float*)d_in[24];
  const float* Wcv = (const float*)d_in[25];
  float* out = (float*)d_out;

  char* ws = (char*)d_ws;
  const size_t CC2 = (size_t)C_DIM * C_DIM * 2;
  const size_t FFC2 = (size_t)FF_DIM * C_DIM * 2;
  unsigned short* Wr_b  = (unsigned short*)(ws + 0 * CC2);
  unsigned short* Wk_b  = (unsigned short*)(ws + 1 * CC2);
  unsigned short* Wv_b  = (unsigned short*)(ws + 2 * CC2);
  unsigned short* Wg_b  = (unsigned short*)(ws + 3 * CC2);
  unsigned short* Wo_b  = (unsigned short*)(ws + 4 * CC2);
  unsigned short* Wcr_b = (unsigned short*)(ws + 5 * CC2);
  unsigned short* Wck_b = (unsigned short*)(ws + 6 * CC2);
  unsigned short* Wcv_b = (unsigned short*)(ws + 6 * CC2 + FFC2);
  char* act = ws + 6 * CC2 + 2 * FFC2;

  const size_t R = (size_t)T_LEN * C_DIM;        // elements
  const size_t RF = R * 4;                       // f32 bytes
  const size_t RB = R * 2;                       // bf16 bytes
  float*          x1   = (float*)(act);                        // alias: wkvo; Pgr; Pgv[0]
  unsigned short* xr_b = (unsigned short*)(act + RF);          // alias: Abuf; Pgo; Pgv[1..2]
  unsigned short* xk_b = (unsigned short*)(act + RF + RB);
  unsigned short* xv_b = (unsigned short*)(act + RF + 2 * RB); // alias: Sbuf
  unsigned short* xg_b = (unsigned short*)(act + RF + 3 * RB);
  float*          rb   = (float*)(act + RF + 4 * RB);          // alias: x2
  float*          kb   = (float*)(act + 2 * RF + 4 * RB);      // alias: xk2_b,xr2_b
  float*          vb   = (float*)(act + 3 * RF + 4 * RB);      // alias: kk_b (vb+gpre)
  float*          gpre = (float*)(act + 4 * RF + 4 * RB);
  unsigned short* zg_b = (unsigned short*)(act + 5 * RF + 4 * RB);
  float*          xnew = (float*)(act + 5 * RF + 5 * RB);
  float*          s1   = (float*)(act + 6 * RF + 5 * RB);
  // aliases
  float*          wkvo  = x1;
  float*          Abuf  = (float*)xr_b;
  float*          Sbuf  = (float*)xv_b;
  float*          x2    = rb;
  unsigned short* xk2_b = (unsigned short*)kb;
  unsigned short* xr2_b = (unsigned short*)((char*)kb + RB);
  unsigned short* kk_b  = (unsigned short*)vb;
  float*          Pgo   = (float*)xr_b;   // 8.4 MB, dead during Wo GEMM
  float*          Pgr   = x1;             // 8.4 MB, dead during Wcr GEMM
  float*          Pgv   = x1;             // 25.2 MB (x1 + xr..xg), dead during Wcv GEMM

  dim3 blk(256);
  const int CCn8 = C_DIM * C_DIM / 8;
  const int FFn8 = FF_DIM * C_DIM / 8;
  const size_t n4 = R / 4;

  // --- weight conversion (one launch) ---
  Cvt8 cv;
  cv.s[0] = Wr;  cv.d[0] = Wr_b;  cv.n8[0] = CCn8;
  cv.s[1] = Wk;  cv.d[1] = Wk_b;  cv.n8[1] = CCn8;
  cv.s[2] = Wv;  cv.d[2] = Wv_b;  cv.n8[2] = CCn8;
  cv.s[3] = Wg;  cv.d[3] = Wg_b;  cv.n8[3] = CCn8;
  cv.s[4] = Wo;  cv.d[4] = Wo_b;  cv.n8[4] = CCn8;
  cv.s[5] = Wcr; cv.d[5] = Wcr_b; cv.n8[5] = CCn8;
  cv.s[6] = Wck; cv.d[6] = Wck_b; cv.n8[6] = FFn8;
  cv.s[7] = Wcv; cv.d[7] = Wcv_b; cv.n8[7] = FFn8;
  cvt_all<<<dim3(512, 8), blk, 0, stream>>>(cv);

  // --- TimeMix ---
  ln_kernel<<<T_LEN, blk, 0, stream>>>(x, ln1_w, ln1_b, x1);
  mix_att<<<T_LEN, blk, 0, stream>>>(x1, att_shift, tm_r, tm_k, tm_v, tm_g,
                                     xr_b, xk_b, xv_b, xg_b);
  GemmBatch g4 = {};
  g4.A[0] = xr_b; g4.B[0] = Wr_b; g4.C[0] = rb;
  g4.A[1] = xk_b; g4.B[1] = Wk_b; g4.C[1] = kb;
  g4.A[2] = xv_b; g4.B[2] = Wv_b; g4.C[2] = vb;
  g4.A[3] = xg_b; g4.B[3] = Wg_b; g4.C[3] = gpre;
  gemm64<0, 1><<<dim3(16, 16, 4), blk, 0, stream>>>(g4, T_LEN, C_DIM, C_DIM, nullptr);

  // chunk-parallel WKV scan (f32)
  wkv_chunk_sum<<<dim3(NCHUNK, H_NUM), blk, 0, stream>>>(kb, vb, time_decay, Abuf);
  wkv_chain<<<H_NUM, blk, 0, stream>>>(Abuf, wkv_state, time_decay, Sbuf);
  wkv_chunk_out<<<dim3(NCHUNK, H_NUM), blk, 0, stream>>>(kb, vb, rb, time_decay, time_faaaa,
                                                         Sbuf, wkvo);

  gn_silu<<<(T_LEN * H_NUM) / 4, blk, 0, stream>>>(wkvo, gpre, gn_w, gn_b, zg_b);

  GemmBatch go = {};
  go.A[0] = zg_b; go.B[0] = Wo_b; go.C[0] = xnew;
  gemm64<0, 2><<<dim3(16, 16, 2), blk, 0, stream>>>(go, T_LEN, C_DIM, C_DIM, Pgo);
  reduce_k<1><<<2048, blk, 0, stream>>>(xnew, Pgo, x, nullptr, n4);

  // --- ChannelMix ---
  ln_kernel<<<T_LEN, blk, 0, stream>>>(xnew, ln2_w, ln2_b, x2);
  mix_cm<<<T_LEN, blk, 0, stream>>>(x2, ffn_shift, cm_k, cm_r, xk2_b, xr2_b);

  GemmBatch gk = {};
  gk.A[0] = xk2_b; gk.B[0] = Wck_b; gk.C[0] = kk_b;
  gemm64<2, 1><<<dim3(56, 16, 1), blk, 0, stream>>>(gk, T_LEN, FF_DIM, C_DIM, nullptr);

  GemmBatch gr = {};
  gr.A[0] = xr2_b; gr.B[0] = Wcr_b; gr.C[0] = s1;
  gemm64<0, 2><<<dim3(16, 16, 2), blk, 0, stream>>>(gr, T_LEN, C_DIM, C_DIM, Pgr);
  reduce_k<0><<<2048, blk, 0, stream>>>(s1, Pgr, nullptr, nullptr, n4);

  GemmBatch gv = {};
  gv.A[0] = kk_b; gv.B[0] = Wcv_b; gv.C[0] = out;
  gemm64<0, 4><<<dim3(16, 16, 4), blk, 0, stream>>>(gv, T_LEN, C_DIM, FF_DIM, Pgv);
  reduce_k<3><<<2048, blk, 0, stream>>>(out, Pgv, s1, xnew, n4);
}

// Round 6
// 383.463 us; speedup vs baseline: 3.6332x; 1.0703x over previous
//
#include <hip/hip_runtime.h>

#define T_LEN 1024
#define C_DIM 2048
#define H_NUM 32
#define HS_DIM 64
#define FF_DIM 7168
#define CHUNK 64
#define NCHUNK (T_LEN / CHUNK)

typedef __attribute__((ext_vector_type(4))) float f32x4;
typedef __attribute__((ext_vector_type(8))) short short8;

__device__ __forceinline__ unsigned short f2bf(float f) {
  unsigned int u = __float_as_uint(f);
  unsigned int r = (u + 0x7FFFu + ((u >> 16) & 1u)) >> 16;
  return (unsigned short)r;
}

__device__ __forceinline__ short8 pack_bf8(float4 a, float4 b) {
  short8 o;
  o[0] = (short)f2bf(a.x); o[1] = (short)f2bf(a.y);
  o[2] = (short)f2bf(a.z); o[3] = (short)f2bf(a.w);
  o[4] = (short)f2bf(b.x); o[5] = (short)f2bf(b.y);
  o[6] = (short)f2bf(b.z); o[7] = (short)f2bf(b.w);
  return o;
}

__device__ __forceinline__ void gl_lds16(const void* g, void* l) {
  __builtin_amdgcn_global_load_lds(
      (const __attribute__((address_space(1))) unsigned int*)g,
      (__attribute__((address_space(3))) unsigned int*)l, 16, 0, 0);
}

// ---------------- f32 -> bf16 convert, all 8 weights, nontemporal ----------------
struct Cvt8 {
  const float* s[8];
  unsigned short* d[8];
  int n8[8];
};

__global__ __launch_bounds__(256) void cvt_all(Cvt8 cv) {
  const int y = blockIdx.y;
  const float* s = cv.s[y];
  unsigned short* d = cv.d[y];
  const int n8 = cv.n8[y];
  for (int i = blockIdx.x * 256 + threadIdx.x; i < n8; i += gridDim.x * 256) {
    const f32x4* p = (const f32x4*)(s + (size_t)i * 8);
    f32x4 a = __builtin_nontemporal_load(p);
    f32x4 b = __builtin_nontemporal_load(p + 1);
    short8 o;
    o[0] = (short)f2bf(a[0]); o[1] = (short)f2bf(a[1]);
    o[2] = (short)f2bf(a[2]); o[3] = (short)f2bf(a[3]);
    o[4] = (short)f2bf(b[0]); o[5] = (short)f2bf(b[1]);
    o[6] = (short)f2bf(b[2]); o[7] = (short)f2bf(b[3]);
    __builtin_nontemporal_store(o, (short8*)(d + (size_t)i * 8));
  }
}

// ---------------- fused LN + TimeMix token-shift (4 bf16 outputs) ----------------
__global__ __launch_bounds__(256) void ln_mix_att(const float* __restrict__ x,
                                                  const float* __restrict__ shift,
                                                  const float* __restrict__ lw,
                                                  const float* __restrict__ lb,
                                                  const float* __restrict__ mr,
                                                  const float* __restrict__ mk,
                                                  const float* __restrict__ mv,
                                                  const float* __restrict__ mg,
                                                  unsigned short* __restrict__ xr,
                                                  unsigned short* __restrict__ xk,
                                                  unsigned short* __restrict__ xv,
                                                  unsigned short* __restrict__ xg) {
  const int t = blockIdx.x;
  const int tid = threadIdx.x;
  const int c0 = tid * 8;
  const float* xrow = x + (size_t)t * C_DIM;
  float cur[8], prv[8];
  *(float4*)&cur[0] = *(const float4*)(xrow + c0);
  *(float4*)&cur[4] = *(const float4*)(xrow + c0 + 4);
  const bool hp = (t > 0);
  const float* prow = hp ? (xrow - C_DIM) : (shift + 0);
  *(float4*)&prv[0] = *(const float4*)(prow + c0);
  *(float4*)&prv[4] = *(const float4*)(prow + c0 + 4);
  float s0 = 0.f, q0 = 0.f, s1 = 0.f, q1 = 0.f;
#pragma unroll
  for (int i = 0; i < 8; ++i) {
    s0 += cur[i]; q0 = __builtin_fmaf(cur[i], cur[i], q0);
    s1 += prv[i]; q1 = __builtin_fmaf(prv[i], prv[i], q1);
  }
#pragma unroll
  for (int o = 1; o < 64; o <<= 1) {
    s0 += __shfl_xor(s0, o); q0 += __shfl_xor(q0, o);
    s1 += __shfl_xor(s1, o); q1 += __shfl_xor(q1, o);
  }
  __shared__ float red[4][4];
  const int wave = tid >> 6, lane = tid & 63;
  if (lane == 0) { red[wave][0] = s0; red[wave][1] = q0; red[wave][2] = s1; red[wave][3] = q1; }
  __syncthreads();
  s0 = red[0][0] + red[1][0] + red[2][0] + red[3][0];
  q0 = red[0][1] + red[1][1] + red[2][1] + red[3][1];
  s1 = red[0][2] + red[1][2] + red[2][2] + red[3][2];
  q1 = red[0][3] + red[1][3] + red[2][3] + red[3][3];
  const float mean0 = s0 * (1.f / C_DIM);
  const float inv0 = rsqrtf(q0 * (1.f / C_DIM) - mean0 * mean0 + 1e-5f);
  const float mean1 = s1 * (1.f / C_DIM);
  const float inv1 = rsqrtf(q1 * (1.f / C_DIM) - mean1 * mean1 + 1e-5f);
  float w8[8], b8[8];
  *(float4*)&w8[0] = *(const float4*)(lw + c0);
  *(float4*)&w8[4] = *(const float4*)(lw + c0 + 4);
  *(float4*)&b8[0] = *(const float4*)(lb + c0);
  *(float4*)&b8[4] = *(const float4*)(lb + c0 + 4);
  float curn[8], prvn[8];
#pragma unroll
  for (int i = 0; i < 8; ++i) {
    curn[i] = (cur[i] - mean0) * inv0 * w8[i] + b8[i];
    prvn[i] = hp ? ((prv[i] - mean1) * inv1 * w8[i] + b8[i]) : prv[i];
  }
  const size_t idx = (size_t)t * C_DIM + c0;
  const float* mixp[4] = {mr, mk, mv, mg};
  unsigned short* dst[4] = {xr, xk, xv, xg};
#pragma unroll
  for (int which = 0; which < 4; ++which) {
    const float* m = mixp[which];
    float o[8];
#pragma unroll
    for (int i = 0; i < 8; ++i) {
      float a = m[c0 + i];
      o[i] = curn[i] * a + prvn[i] * (1.f - a);
    }
    *(short8*)(dst[which] + idx) = pack_bf8(*(float4*)&o[0], *(float4*)&o[4]);
  }
}

// ---------------- fused LN + ChannelMix token-shift (2 bf16 outputs) ----------------
__global__ __launch_bounds__(256) void ln_mix_cm(const float* __restrict__ x,
                                                 const float* __restrict__ shift,
                                                 const float* __restrict__ lw,
                                                 const float* __restrict__ lb,
                                                 const float* __restrict__ mk,
                                                 const float* __restrict__ mr,
                                                 unsigned short* __restrict__ xk2,
                                                 unsigned short* __restrict__ xr2) {
  const int t = blockIdx.x;
  const int tid = threadIdx.x;
  const int c0 = tid * 8;
  const float* xrow = x + (size_t)t * C_DIM;
  float cur[8], prv[8];
  *(float4*)&cur[0] = *(const float4*)(xrow + c0);
  *(float4*)&cur[4] = *(const float4*)(xrow + c0 + 4);
  const bool hp = (t > 0);
  const float* prow = hp ? (xrow - C_DIM) : (shift + 0);
  *(float4*)&prv[0] = *(const float4*)(prow + c0);
  *(float4*)&prv[4] = *(const float4*)(prow + c0 + 4);
  float s0 = 0.f, q0 = 0.f, s1 = 0.f, q1 = 0.f;
#pragma unroll
  for (int i = 0; i < 8; ++i) {
    s0 += cur[i]; q0 = __builtin_fmaf(cur[i], cur[i], q0);
    s1 += prv[i]; q1 = __builtin_fmaf(prv[i], prv[i], q1);
  }
#pragma unroll
  for (int o = 1; o < 64; o <<= 1) {
    s0 += __shfl_xor(s0, o); q0 += __shfl_xor(q0, o);
    s1 += __shfl_xor(s1, o); q1 += __shfl_xor(q1, o);
  }
  __shared__ float red[4][4];
  const int wave = tid >> 6, lane = tid & 63;
  if (lane == 0) { red[wave][0] = s0; red[wave][1] = q0; red[wave][2] = s1; red[wave][3] = q1; }
  __syncthreads();
  s0 = red[0][0] + red[1][0] + red[2][0] + red[3][0];
  q0 = red[0][1] + red[1][1] + red[2][1] + red[3][1];
  s1 = red[0][2] + red[1][2] + red[2][2] + red[3][2];
  q1 = red[0][3] + red[1][3] + red[2][3] + red[3][3];
  const float mean0 = s0 * (1.f / C_DIM);
  const float inv0 = rsqrtf(q0 * (1.f / C_DIM) - mean0 * mean0 + 1e-5f);
  const float mean1 = s1 * (1.f / C_DIM);
  const float inv1 = rsqrtf(q1 * (1.f / C_DIM) - mean1 * mean1 + 1e-5f);
  float w8[8], b8[8];
  *(float4*)&w8[0] = *(const float4*)(lw + c0);
  *(float4*)&w8[4] = *(const float4*)(lw + c0 + 4);
  *(float4*)&b8[0] = *(const float4*)(lb + c0);
  *(float4*)&b8[4] = *(const float4*)(lb + c0 + 4);
  float ok[8], orr[8];
#pragma unroll
  for (int i = 0; i < 8; ++i) {
    const float cn = (cur[i] - mean0) * inv0 * w8[i] + b8[i];
    const float pn = hp ? ((prv[i] - mean1) * inv1 * w8[i] + b8[i]) : prv[i];
    float a = mk[c0 + i];
    ok[i] = cn * a + pn * (1.f - a);
    a = mr[c0 + i];
    orr[i] = cn * a + pn * (1.f - a);
  }
  const size_t idx = (size_t)t * C_DIM + c0;
  *(short8*)(xk2 + idx) = pack_bf8(*(float4*)&ok[0], *(float4*)&ok[4]);
  *(short8*)(xr2 + idx) = pack_bf8(*(float4*)&orr[0], *(float4*)&orr[4]);
}

// ======================= Chunk-parallel WKV v5 scan (f32) =======================
__global__ __launch_bounds__(256) void wkv_chunk_sum(const float* __restrict__ kin,
                                                     const float* __restrict__ vin,
                                                     const float* __restrict__ decay,
                                                     float* __restrict__ Abuf) {
  const int c = blockIdx.x, h = blockIdx.y;
  const int tid = threadIdx.x;
  const int vcol = tid >> 2, kg = tid & 3;
  __shared__ float ks[CHUNK][HS_DIM];
  __shared__ float vs[CHUNK][HS_DIM];
  for (int i = tid; i < CHUNK * HS_DIM / 4; i += 256) {
    int row = i >> 4, q = i & 15;
    size_t g = (size_t)(c * CHUNK + row) * C_DIM + h * HS_DIM + q * 4;
    *(float4*)&ks[row][q * 4] = *(const float4*)(kin + g);
    *(float4*)&vs[row][q * 4] = *(const float4*)(vin + g);
  }
  float w16[16], s[16];
#pragma unroll
  for (int j = 0; j < 16; ++j) {
    w16[j] = expf(-expf(decay[h * HS_DIM + kg * 16 + j]));
    s[j] = 0.f;
  }
  __syncthreads();
  for (int t = 0; t < CHUNK; ++t) {
    const float vt = vs[t][vcol];
    const float4* kp = (const float4*)&ks[t][kg * 16];
#pragma unroll
    for (int q = 0; q < 4; ++q) {
      float4 k4 = kp[q];
      s[q * 4 + 0] = __builtin_fmaf(s[q * 4 + 0], w16[q * 4 + 0], k4.x * vt);
      s[q * 4 + 1] = __builtin_fmaf(s[q * 4 + 1], w16[q * 4 + 1], k4.y * vt);
      s[q * 4 + 2] = __builtin_fmaf(s[q * 4 + 2], w16[q * 4 + 2], k4.z * vt);
      s[q * 4 + 3] = __builtin_fmaf(s[q * 4 + 3], w16[q * 4 + 3], k4.w * vt);
    }
  }
  const size_t base = (((size_t)h * NCHUNK + c) * HS_DIM + kg * 16) * HS_DIM + vcol;
#pragma unroll
  for (int j = 0; j < 16; ++j) Abuf[base + (size_t)j * HS_DIM] = s[j];
}

__global__ __launch_bounds__(256) void wkv_chain(const float* __restrict__ Abuf,
                                                 const float* __restrict__ s0,
                                                 const float* __restrict__ decay,
                                                 float* __restrict__ Sbuf) {
  const int h = blockIdx.x;
  const int tid = threadIdx.x;
  const int vcol = tid >> 2, kg = tid & 3;
  float wL[16], s[16];
#pragma unroll
  for (int j = 0; j < 16; ++j) {
    int kidx = kg * 16 + j;
    wL[j] = expf(-(float)CHUNK * expf(decay[h * HS_DIM + kidx]));
    s[j] = s0[((size_t)h * HS_DIM + kidx) * HS_DIM + vcol];
  }
  for (int c = 0; c < NCHUNK; ++c) {
    const size_t base = (((size_t)h * NCHUNK + c) * HS_DIM + kg * 16) * HS_DIM + vcol;
#pragma unroll
    for (int j = 0; j < 16; ++j) {
      Sbuf[base + (size_t)j * HS_DIM] = s[j];
      s[j] = __builtin_fmaf(s[j], wL[j], Abuf[base + (size_t)j * HS_DIM]);
    }
  }
}

__global__ __launch_bounds__(256) void wkv_chunk_out(const float* __restrict__ kin,
                                                     const float* __restrict__ vin,
                                                     const float* __restrict__ rin,
                                                     const float* __restrict__ decay,
                                                     const float* __restrict__ faaaa,
                                                     const float* __restrict__ Sbuf,
                                                     float* __restrict__ outp) {
  const int c = blockIdx.x, h = blockIdx.y;
  const int tid = threadIdx.x;
  const int vcol = tid >> 2, kg = tid & 3;
  __shared__ float ks[CHUNK][HS_DIM];
  __shared__ float rs[CHUNK][HS_DIM];
  __shared__ float vs[CHUNK][HS_DIM];
  for (int i = tid; i < CHUNK * HS_DIM / 4; i += 256) {
    int row = i >> 4, q = i & 15;
    size_t g = (size_t)(c * CHUNK + row) * C_DIM + h * HS_DIM + q * 4;
    *(float4*)&ks[row][q * 4] = *(const float4*)(kin + g);
    *(float4*)&rs[row][q * 4] = *(const float4*)(rin + g);
    *(float4*)&vs[row][q * 4] = *(const float4*)(vin + g);
  }
  float w16[16], u16[16], s[16];
  const size_t sbase = (((size_t)h * NCHUNK + c) * HS_DIM + kg * 16) * HS_DIM + vcol;
#pragma unroll
  for (int j = 0; j < 16; ++j) {
    int kidx = kg * 16 + j;
    w16[j] = expf(-expf(decay[h * HS_DIM + kidx]));
    u16[j] = faaaa[h * HS_DIM + kidx];
    s[j] = Sbuf[sbase + (size_t)j * HS_DIM];
  }
  __syncthreads();
  for (int t = 0; t < CHUNK; ++t) {
    const float vt = vs[t][vcol];
    const float4* kp = (const float4*)&ks[t][kg * 16];
    const float4* rp = (const float4*)&rs[t][kg * 16];
    float acc = 0.f, ruk = 0.f;
#pragma unroll
    for (int q = 0; q < 4; ++q) {
      float4 k4 = kp[q], r4 = rp[q];
      acc = __builtin_fmaf(r4.x, s[q * 4 + 0], acc);
      ruk = __builtin_fmaf(r4.x * u16[q * 4 + 0], k4.x, ruk);
      s[q * 4 + 0] = __builtin_fmaf(s[q * 4 + 0], w16[q * 4 + 0], k4.x * vt);
      acc = __builtin_fmaf(r4.y, s[q * 4 + 1], acc);
      ruk = __builtin_fmaf(r4.y * u16[q * 4 + 1], k4.y, ruk);
      s[q * 4 + 1] = __builtin_fmaf(s[q * 4 + 1], w16[q * 4 + 1], k4.y * vt);
      acc = __builtin_fmaf(r4.z, s[q * 4 + 2], acc);
      ruk = __builtin_fmaf(r4.z * u16[q * 4 + 2], k4.z, ruk);
      s[q * 4 + 2] = __builtin_fmaf(s[q * 4 + 2], w16[q * 4 + 2], k4.z * vt);
      acc = __builtin_fmaf(r4.w, s[q * 4 + 3], acc);
      ruk = __builtin_fmaf(r4.w * u16[q * 4 + 3], k4.w, ruk);
      s[q * 4 + 3] = __builtin_fmaf(s[q * 4 + 3], w16[q * 4 + 3], k4.w * vt);
    }
    float part = __builtin_fmaf(ruk, vt, acc);
    part += __shfl_xor(part, 1);
    part += __shfl_xor(part, 2);
    if (kg == 0) outp[(size_t)(c * CHUNK + t) * C_DIM + h * HS_DIM + vcol] = part;
  }
}

// ---------------- GroupNorm(out/8) * gn_w + gn_b, times silu(g) -> bf16 ----------------
__global__ __launch_bounds__(256) void gn_silu(const float* __restrict__ wkv,
                                               const float* __restrict__ gpre,
                                               const float* __restrict__ gw,
                                               const float* __restrict__ gb,
                                               unsigned short* __restrict__ zg) {
  const int idx = blockIdx.x * 4 + (threadIdx.x >> 6);  // group index = t*32 + h
  const int lane = threadIdx.x & 63;
  const int t = idx >> 5, h = idx & 31;
  const int c = h * HS_DIM + lane;
  const size_t off = (size_t)t * C_DIM + c;
  float z = wkv[off] * 0.125f;
  float s = z, sq = z * z;
#pragma unroll
  for (int o = 1; o < 64; o <<= 1) { s += __shfl_xor(s, o); sq += __shfl_xor(sq, o); }
  const float mean = s * (1.f / HS_DIM);
  const float var = sq * (1.f / HS_DIM) - mean * mean;
  const float val = (z - mean) * rsqrtf(var + 1e-5f) * gw[c] + gb[c];
  const float g = gpre[off];
  const float sig = 1.f / (1.f + __expf(-g));
  zg[off] = f2bf(val * (g * sig));
}

// ===== bf16 GEMM, BM=128 BN=128 BK=32, wave tile 64x64, dbuf LDS + XOR swizzle =====
// C[M,N] = A[M,K] * B[N,K]^T.  EPI: 0 = f32 raw; 2 = bf16 relu(acc)^2.
// SPLITK>1: blockIdx.z = batch*SPLITK + s; split 0 writes raw f32 C, splits >=1
// write raw f32 partials to P + (s-1)*M*N. Epilogue applied by reduce kernels.
struct GemmBatch {
  const unsigned short* A[4];
  const unsigned short* B[4];
  void* C[4];
};

template <int EPI, int SPLITK>
__global__ __launch_bounds__(256) void gemm128(GemmBatch gb, int M, int N, int K,
                                               float* __restrict__ P) {
  const int zz = blockIdx.z;
  const int s = zz % SPLITK, zb = zz / SPLITK;
  const int Ks = K / SPLITK;
  const int k0 = s * Ks;
  const unsigned short* __restrict__ A = gb.A[zb];
  const unsigned short* __restrict__ B = gb.B[zb];

  __shared__ unsigned short As[2][128 * 32];  // 8 KB per buf
  __shared__ unsigned short Bs[2][128 * 32];

  const int tid = threadIdx.x;
  const int l = tid & 63;
  const int w = tid >> 6;
  const int wm = w >> 1, wn = w & 1;
  const int m0 = blockIdx.y * 128, n0 = blockIdx.x * 128;
  const int lrow = l & 15;
  const size_t Kb = (size_t)K * 2;

  // staging: issue i covers rows [i*64 + w*16, +16); lane l -> row + l/4, slot l&3
  // LDS linear; global source pre-swizzled: slot ^= (row&3)
  const int srow = w * 16 + (l >> 2);
  const int kslot = ((l & 3) ^ ((l >> 2) & 3)) * 16;
  const char* Agl = (const char*)A + (size_t)(m0 + srow) * Kb + kslot;
  const char* Bgl = (const char*)B + (size_t)(n0 + srow) * Kb + kslot;

  f32x4 acc[4][4];
#pragma unroll
  for (int m = 0; m < 4; ++m)
#pragma unroll
    for (int n = 0; n < 4; ++n) acc[m][n] = (f32x4){0.f, 0.f, 0.f, 0.f};

#define STG(buf, kk)                                                       \
  {                                                                        \
    const size_t kb2 = (size_t)(kk) * 2;                                   \
    gl_lds16(Agl + kb2, (char*)&As[buf][0] + w * 1024);                    \
    gl_lds16(Agl + 64 * Kb + kb2, (char*)&As[buf][0] + 4096 + w * 1024);   \
    gl_lds16(Bgl + kb2, (char*)&Bs[buf][0] + w * 1024);                    \
    gl_lds16(Bgl + 64 * Kb + kb2, (char*)&Bs[buf][0] + 4096 + w * 1024);   \
  }

  STG(0, k0);
  __syncthreads();

  const int nt = Ks / 32;
  for (int t = 0; t < nt; ++t) {
    const int buf = t & 1;
    if (t + 1 < nt) STG(buf ^ 1, k0 + (t + 1) * 32);
    const char* Ab = (const char*)&As[buf][0];
    const char* Bb = (const char*)&Bs[buf][0];
    const int kb = (l >> 4) * 16;
    const int kbs = kb ^ ((lrow & 3) << 4);
    short8 af[4], bfr[4];
#pragma unroll
    for (int m = 0; m < 4; ++m) {
      const int row = wm * 64 + m * 16 + lrow;
      af[m] = *(const short8*)(Ab + row * 64 + kbs);
    }
#pragma unroll
    for (int n = 0; n < 4; ++n) {
      const int row = wn * 64 + n * 16 + lrow;
      bfr[n] = *(const short8*)(Bb + row * 64 + kbs);
    }
#pragma unroll
    for (int m = 0; m < 4; ++m)
#pragma unroll
      for (int n = 0; n < 4; ++n)
        acc[m][n] = __builtin_amdgcn_mfma_f32_16x16x32_bf16(af[m], bfr[n], acc[m][n], 0, 0, 0);
    __syncthreads();
  }
#undef STG

  float* Co;
  if (SPLITK > 1)
    Co = (s == 0) ? (float*)gb.C[zb] : P + (size_t)(s - 1) * M * N;
  else
    Co = (float*)gb.C[zb];

#pragma unroll
  for (int m = 0; m < 4; ++m) {
#pragma unroll
    for (int n = 0; n < 4; ++n) {
#pragma unroll
      for (int j = 0; j < 4; ++j) {
        const int row = m0 + wm * 64 + m * 16 + ((l >> 4) << 2) + j;
        const int col = n0 + wn * 64 + n * 16 + lrow;
        const size_t idx = (size_t)row * N + col;
        const float v = acc[m][n][j];
        if (EPI == 2 && SPLITK == 1) {
          float tpos = v > 0.f ? v : 0.f;
          ((unsigned short*)gb.C[zb])[idx] = f2bf(tpos * tpos);
        } else {
          Co[idx] = v;
        }
      }
    }
  }
}

// ---------------- split-K reduce + fused epilogues ----------------
// MODE 0: C += P ; MODE 1: C += P + E0 ; MODE 3: C = E1 + sig(E0)*(C+P0+P1+P2)
template <int MODE>
__global__ __launch_bounds__(256) void reduce_k(float* __restrict__ C,
                                                const float* __restrict__ P,
                                                const float* __restrict__ E0,
                                                const float* __restrict__ E1,
                                                size_t n4) {
  for (size_t i = (size_t)blockIdx.x * 256 + threadIdx.x; i < n4;
       i += (size_t)gridDim.x * 256) {
    float4 c = ((const float4*)C)[i];
    float4 p = ((const float4*)P)[i];
    if (MODE == 0) {
      c.x += p.x; c.y += p.y; c.z += p.z; c.w += p.w;
    } else if (MODE == 1) {
      float4 e = ((const float4*)E0)[i];
      c.x += p.x + e.x; c.y += p.y + e.y; c.z += p.z + e.z; c.w += p.w + e.w;
    } else {
      float4 p1 = ((const float4*)P)[i + n4];
      float4 p2 = ((const float4*)P)[i + 2 * n4];
      float4 e0 = ((const float4*)E0)[i];
      float4 e1 = ((const float4*)E1)[i];
      c.x = e1.x + (1.f / (1.f + __expf(-e0.x))) * (c.x + p.x + p1.x + p2.x);
      c.y = e1.y + (1.f / (1.f + __expf(-e0.y))) * (c.y + p.y + p1.y + p2.y);
      c.z = e1.z + (1.f / (1.f + __expf(-e0.z))) * (c.z + p.z + p1.z + p2.z);
      c.w = e1.w + (1.f / (1.f + __expf(-e0.w))) * (c.w + p.w + p1.w + p2.w);
    }
    ((float4*)C)[i] = c;
  }
}

extern "C" void kernel_launch(void* const* d_in, const int* in_sizes, int n_in,
                              void* d_out, int out_size, void* d_ws, size_t ws_size,
                              hipStream_t stream) {
  (void)in_sizes; (void)n_in; (void)out_size; (void)ws_size;
  const float* x         = (const float*)d_in[0];
  const float* att_shift = (const float*)d_in[1];
  const float* wkv_state = (const float*)d_in[2];
  const float* ffn_shift = (const float*)d_in[3];
  const float* ln1_w = (const float*)d_in[4];
  const float* ln1_b = (const float*)d_in[5];
  const float* ln2_w = (const float*)d_in[6];
  const float* ln2_b = (const float*)d_in[7];
  const float* tm_k = (const float*)d_in[8];
  const float* tm_v = (const float*)d_in[9];
  const float* tm_r = (const float*)d_in[10];
  const float* tm_g = (const float*)d_in[11];
  const float* time_decay = (const float*)d_in[12];
  const float* time_faaaa = (const float*)d_in[13];
  const float* Wr = (const float*)d_in[14];
  const float* Wk = (const float*)d_in[15];
  const float* Wv = (const float*)d_in[16];
  const float* Wo = (const float*)d_in[17];
  const float* Wg = (const float*)d_in[18];
  const float* gn_w = (const float*)d_in[19];
  const float* gn_b = (const float*)d_in[20];
  const float* cm_k = (const float*)d_in[21];
  const float* cm_r = (const float*)d_in[22];
  const float* Wck = (const float*)d_in[23];
  const float* Wcr = (const float*)d_in[24];
  const float* Wcv = (const float*)d_in[25];
  float* out = (float*)d_out;

  char* ws = (char*)d_ws;
  const size_t CC2 = (size_t)C_DIM * C_DIM * 2;
  const size_t FFC2 = (size_t)FF_DIM * C_DIM * 2;
  unsigned short* Wr_b  = (unsigned short*)(ws + 0 * CC2);
  unsigned short* Wk_b  = (unsigned short*)(ws + 1 * CC2);
  unsigned short* Wv_b  = (unsigned short*)(ws + 2 * CC2);
  unsigned short* Wg_b  = (unsigned short*)(ws + 3 * CC2);
  unsigned short* Wo_b  = (unsigned short*)(ws + 4 * CC2);
  unsigned short* Wcr_b = (unsigned short*)(ws + 5 * CC2);
  unsigned short* Wck_b = (unsigned short*)(ws + 6 * CC2);
  unsigned short* Wcv_b = (unsigned short*)(ws + 6 * CC2 + FFC2);
  char* act = ws + 6 * CC2 + 2 * FFC2;

  const size_t R = (size_t)T_LEN * C_DIM;        // elements
  const size_t RF = R * 4;                       // f32 bytes
  const size_t RB = R * 2;                       // bf16 bytes
  float*          x1   = (float*)(act);                        // wkvo; P-partials
  unsigned short* xr_b = (unsigned short*)(act + RF);          // Abuf; P-partials
  unsigned short* xk_b = (unsigned short*)(act + RF + RB);
  unsigned short* xv_b = (unsigned short*)(act + RF + 2 * RB); // Sbuf
  unsigned short* xg_b = (unsigned short*)(act + RF + 3 * RB);
  float*          rb   = (float*)(act + RF + 4 * RB);
  float*          kb   = (float*)(act + 2 * RF + 4 * RB);      // xk2_b,xr2_b
  float*          vb   = (float*)(act + 3 * RF + 4 * RB);      // kk_b (vb+gpre)
  float*          gpre = (float*)(act + 4 * RF + 4 * RB);
  unsigned short* zg_b = (unsigned short*)(act + 5 * RF + 4 * RB);
  float*          xnew = (float*)(act + 5 * RF + 5 * RB);
  float*          s1   = (float*)(act + 6 * RF + 5 * RB);
  // aliases
  float*          wkvo  = x1;
  float*          Abuf  = (float*)xr_b;
  float*          Sbuf  = (float*)xv_b;
  unsigned short* xk2_b = (unsigned short*)kb;
  unsigned short* xr2_b = (unsigned short*)((char*)kb + RB);
  unsigned short* kk_b  = (unsigned short*)vb;
  float*          Pgo   = (float*)xr_b;   // dead during Wo GEMM
  float*          Pgr   = x1;             // dead during Wcr GEMM
  float*          Pgv   = x1;             // 25.2 MB (x1 + xr..xg), dead during Wcv GEMM

  dim3 blk(256);
  const int CCn8 = C_DIM * C_DIM / 8;
  const int FFn8 = FF_DIM * C_DIM / 8;
  const size_t n4 = R / 4;

  // --- weight conversion (one launch, nontemporal) ---
  Cvt8 cv;
  cv.s[0] = Wr;  cv.d[0] = Wr_b;  cv.n8[0] = CCn8;
  cv.s[1] = Wk;  cv.d[1] = Wk_b;  cv.n8[1] = CCn8;
  cv.s[2] = Wv;  cv.d[2] = Wv_b;  cv.n8[2] = CCn8;
  cv.s[3] = Wg;  cv.d[3] = Wg_b;  cv.n8[3] = CCn8;
  cv.s[4] = Wo;  cv.d[4] = Wo_b;  cv.n8[4] = CCn8;
  cv.s[5] = Wcr; cv.d[5] = Wcr_b; cv.n8[5] = CCn8;
  cv.s[6] = Wck; cv.d[6] = Wck_b; cv.n8[6] = FFn8;
  cv.s[7] = Wcv; cv.d[7] = Wcv_b; cv.n8[7] = FFn8;
  cvt_all<<<dim3(1024, 8), blk, 0, stream>>>(cv);

  // --- TimeMix ---
  ln_mix_att<<<T_LEN, blk, 0, stream>>>(x, att_shift, ln1_w, ln1_b,
                                        tm_r, tm_k, tm_v, tm_g,
                                        xr_b, xk_b, xv_b, xg_b);
  GemmBatch g4 = {};
  g4.A[0] = xr_b; g4.B[0] = Wr_b; g4.C[0] = rb;
  g4.A[1] = xk_b; g4.B[1] = Wk_b; g4.C[1] = kb;
  g4.A[2] = xv_b; g4.B[2] = Wv_b; g4.C[2] = vb;
  g4.A[3] = xg_b; g4.B[3] = Wg_b; g4.C[3] = gpre;
  gemm128<0, 1><<<dim3(16, 8, 4), blk, 0, stream>>>(g4, T_LEN, C_DIM, C_DIM, nullptr);

  // chunk-parallel WKV scan (f32)
  wkv_chunk_sum<<<dim3(NCHUNK, H_NUM), blk, 0, stream>>>(kb, vb, time_decay, Abuf);
  wkv_chain<<<H_NUM, blk, 0, stream>>>(Abuf, wkv_state, time_decay, Sbuf);
  wkv_chunk_out<<<dim3(NCHUNK, H_NUM), blk, 0, stream>>>(kb, vb, rb, time_decay, time_faaaa,
                                                         Sbuf, wkvo);

  gn_silu<<<(T_LEN * H_NUM) / 4, blk, 0, stream>>>(wkvo, gpre, gn_w, gn_b, zg_b);

  GemmBatch go = {};
  go.A[0] = zg_b; go.B[0] = Wo_b; go.C[0] = xnew;
  gemm128<0, 2><<<dim3(16, 8, 2), blk, 0, stream>>>(go, T_LEN, C_DIM, C_DIM, Pgo);
  reduce_k<1><<<2048, blk, 0, stream>>>(xnew, Pgo, x, nullptr, n4);

  // --- ChannelMix ---
  ln_mix_cm<<<T_LEN, blk, 0, stream>>>(xnew, ffn_shift, ln2_w, ln2_b, cm_k, cm_r,
                                       xk2_b, xr2_b);

  GemmBatch gk = {};
  gk.A[0] = xk2_b; gk.B[0] = Wck_b; gk.C[0] = kk_b;
  gemm128<2, 1><<<dim3(56, 8, 1), blk, 0, stream>>>(gk, T_LEN, FF_DIM, C_DIM, nullptr);

  GemmBatch gr = {};
  gr.A[0] = xr2_b; gr.B[0] = Wcr_b; gr.C[0] = s1;
  gemm128<0, 2><<<dim3(16, 8, 2), blk, 0, stream>>>(gr, T_LEN, C_DIM, C_DIM, Pgr);
  reduce_k<0><<<2048, blk, 0, stream>>>(s1, Pgr, nullptr, nullptr, n4);

  GemmBatch gv = {};
  gv.A[0] = kk_b; gv.B[0] = Wcv_b; gv.C[0] = out;
  gemm128<0, 4><<<dim3(16, 8, 4), blk, 0, stream>>>(gv, T_LEN, C_DIM, FF_DIM, Pgv);
  reduce_k<3><<<2048, blk, 0, stream>>>(out, Pgv, s1, xnew, n4);
}